// Round 1
// 798.879 us; speedup vs baseline: 1.2446x; 1.2446x over previous
//
#include <hip/hip_runtime.h>
#include <hip/hip_bf16.h>
#include <float.h>

#define HEADS 4
#define DK 32

static constexpr float kBeta = 1.0f;
static constexpr float kNeg  = 0.2f;
static constexpr float kEps  = 1e-12f;

__device__ __forceinline__ float bf2f(unsigned short v) {
  return __uint_as_float((unsigned)v << 16);
}
__device__ __forceinline__ float2 bfp2(unsigned u) {
  return make_float2(__uint_as_float(u << 16), __uint_as_float(u & 0xFFFF0000u));
}
// order-preserving float <-> uint key for atomicMax
__device__ __forceinline__ unsigned fkey(float x) {
  unsigned u = __float_as_uint(x);
  return (u & 0x80000000u) ? ~u : (u | 0x80000000u);
}
__device__ __forceinline__ float funkey(unsigned k) {
  unsigned u = (k & 0x80000000u) ? (k & 0x7fffffffu) : ~k;
  return __uint_as_float(u);
}

// ---- K0a: edge layout detect (int64 -> odd words all 0) ----------------------
__global__ __launch_bounds__(256) void k_detect_edges(const int* __restrict__ ei32,
                                                      int* __restrict__ eflag, int E) {
  int i = blockIdx.x * 256 + threadIdx.x;  // [0, 4096)
  if (2 * i + 1 < 2 * E && ei32[2 * i + 1] != 0) atomicOr(eflag, 1);
}

// ---- K0b: float dtype detect: fp32 words have random mantissa bits 14..7 -----
__global__ __launch_bounds__(256) void k_detect_dtype(const unsigned* __restrict__ Hw,
                                                      int* __restrict__ dflag, int nw) {
  int i = blockIdx.x * 256 + threadIdx.x;
  if (i < nw && ((Hw[i] >> 7) & 0xFFu) == 0xFFu) atomicOr(dflag, 1);
}

// ---- K0c: normalize edge index into int32 src/dst + degree histogram ---------
__global__ __launch_bounds__(256) void k_cvt(const int* __restrict__ ei32,
                                             const int* __restrict__ eflag,
                                             int* __restrict__ src_i,
                                             int* __restrict__ dst_i,
                                             int* __restrict__ deg, int E) {
  int i = blockIdx.x * 256 + threadIdx.x;
  if (i >= E) return;
  int s, d;
  if (*eflag) { s = ei32[i];     d = ei32[E + i]; }
  else        { s = ei32[2 * i]; d = ei32[2 * E + 2 * i]; }
  src_i[i] = s;
  dst_i[i] = d;
  atomicAdd(deg + d, 1);
}

// ---- K0d: param convert to fp32 (identity copy if already fp32) --------------
__global__ __launch_bounds__(256) void k_f32cvt(const void* __restrict__ in,
                                                float* __restrict__ out,
                                                const int* __restrict__ dflag, int n) {
  int i = blockIdx.x * 256 + threadIdx.x;
  if (i >= n) return;
  out[i] = (*dflag) ? ((const float*)in)[i] : bf2f(((const unsigned short*)in)[i]);
}

// ---- K0e: exclusive scan of deg -> row_ptr, cursor (single block) ------------
__global__ __launch_bounds__(1024) void k_scan(const int* __restrict__ deg,
                                               int* __restrict__ row_ptr,
                                               int* __restrict__ cursor, int N) {
  __shared__ int part[1024];
  const int t = threadIdx.x;
  const int C = (N + 1023) >> 10;
  const int b = t * C;
  int s = 0;
  for (int i = 0; i < C; ++i) {
    int idx = b + i;
    if (idx < N) s += deg[idx];
  }
  part[t] = s;
  __syncthreads();
  for (int off = 1; off < 1024; off <<= 1) {
    int v = (t >= off) ? part[t - off] : 0;
    __syncthreads();
    part[t] += v;
    __syncthreads();
  }
  int run = (t == 0) ? 0 : part[t - 1];
  for (int i = 0; i < C; ++i) {
    int idx = b + i;
    if (idx < N) {
      row_ptr[idx] = run;
      cursor[idx] = run;
      run += deg[idx];
    }
  }
  if (t == 1023) row_ptr[N] = part[1023];
}

// ---- K0f: fill CSR edge lists ------------------------------------------------
__global__ __launch_bounds__(256) void k_fill(const int* __restrict__ dst,
                                              int* __restrict__ cursor,
                                              int* __restrict__ eidx, int E) {
  int e = blockIdx.x * 256 + threadIdx.x;
  if (e >= E) return;
  int pos = atomicAdd(cursor + dst[e], 1);
  eidx[pos] = e;
}

// ---- K1: H_proj = H @ W.T (dual-dtype H staging; W pre-converted fp32) -------
__global__ __launch_bounds__(256) void k_proj(const void* __restrict__ Hraw,
                                              const float* __restrict__ Wf,
                                              const int* __restrict__ dflag,
                                              float* __restrict__ Hproj, int N) {
  __shared__ float Ht[32][260];
  const int t = threadIdx.x;
  const int nb = blockIdx.x * 32;
  const int dt = *dflag;
  if (dt) {  // fp32 input
    const float4* __restrict__ H4 = (const float4*)Hraw;
#pragma unroll
    for (int i = 0; i < 8; ++i) {
      int f = t + i * 256;
      int r = f >> 6, kq = f & 63;
      float4 v = make_float4(0.f, 0.f, 0.f, 0.f);
      if (nb + r < N) v = H4[(size_t)(nb + r) * 64 + kq];
      *(float4*)&Ht[r][4 * kq] = v;
    }
  } else {   // bf16 input
    const uint4* __restrict__ H8 = (const uint4*)Hraw;
#pragma unroll
    for (int i = 0; i < 4; ++i) {
      int g = t + i * 256;
      int r = g >> 5, c8 = g & 31;
      uint4 v = make_uint4(0u, 0u, 0u, 0u);
      if (nb + r < N) v = H8[(size_t)(nb + r) * 32 + c8];
      float2 f0 = bfp2(v.x), f1 = bfp2(v.y), f2 = bfp2(v.z), f3 = bfp2(v.w);
      *(float4*)&Ht[r][c8 * 8 + 0] = make_float4(f0.x, f0.y, f1.x, f1.y);
      *(float4*)&Ht[r][c8 * 8 + 4] = make_float4(f2.x, f2.y, f3.x, f3.y);
    }
  }
  __syncthreads();
  const int c0 = (t & 31) * 4;
  const int n0 = (t >> 5) * 4;
  float acc[4][4];
#pragma unroll
  for (int n = 0; n < 4; ++n)
#pragma unroll
    for (int j = 0; j < 4; ++j) acc[n][j] = 0.f;
  const float4* __restrict__ W4 = (const float4*)Wf;
#pragma unroll 4
  for (int kq = 0; kq < 64; ++kq) {
    float4 w0 = W4[(size_t)(c0 + 0) * 64 + kq];
    float4 w1 = W4[(size_t)(c0 + 1) * 64 + kq];
    float4 w2 = W4[(size_t)(c0 + 2) * 64 + kq];
    float4 w3 = W4[(size_t)(c0 + 3) * 64 + kq];
#pragma unroll
    for (int n = 0; n < 4; ++n) {
      float4 h = *(const float4*)&Ht[n0 + n][4 * kq];
      acc[n][0] += h.x * w0.x + h.y * w0.y + h.z * w0.z + h.w * w0.w;
      acc[n][1] += h.x * w1.x + h.y * w1.y + h.z * w1.z + h.w * w1.w;
      acc[n][2] += h.x * w2.x + h.y * w2.y + h.z * w2.z + h.w * w2.w;
      acc[n][3] += h.x * w3.x + h.y * w3.y + h.z * w3.z + h.w * w3.w;
    }
  }
#pragma unroll
  for (int n = 0; n < 4; ++n) {
    int row = nb + n0 + n;
    if (row < N)
      *(float4*)&Hproj[(size_t)row * 128 + c0] =
          make_float4(acc[n][0], acc[n][1], acc[n][2], acc[n][3]);
  }
}

// ---- K2: per-node attention dots + msg base ----------------------------------
__global__ __launch_bounds__(256) void k_node(const float* __restrict__ Hproj,
                                              const float* __restrict__ af,   // [a_src(128)|a_dst(128)]
                                              const float* __restrict__ msgwf,
                                              float* __restrict__ s_src,
                                              float* __restrict__ s_dst,
                                              float* __restrict__ msgb, int N) {
  const int l = threadIdx.x & 63;
  const int wb = threadIdx.x >> 6;
  const int n = (blockIdx.x << 2) + wb;
  if (n >= N) return;
  const float* row = Hproj + (size_t)n * 128;
  float h0 = row[l], h1 = row[64 + l];
  float p0 = h0 * af[l],       p1 = h1 * af[64 + l];
  float q0 = h0 * af[128 + l], q1 = h1 * af[192 + l];
#pragma unroll
  for (int off = 16; off; off >>= 1) {
    p0 += __shfl_xor(p0, off);
    p1 += __shfl_xor(p1, off);
    q0 += __shfl_xor(q0, off);
    q1 += __shfl_xor(q1, off);
  }
  if (l == 0)  { s_src[n*4+0] = p0; s_src[n*4+2] = p1; s_dst[n*4+0] = q0; s_dst[n*4+2] = q1; }
  if (l == 32) { s_src[n*4+1] = p0; s_src[n*4+3] = p1; s_dst[n*4+1] = q0; s_dst[n*4+3] = q1; }
  float t4 = h0 + __shfl_xor(h0, 32) + h1 + __shfl_xor(h1, 32);
  float hbar = 0.25f * t4;  // lanes 0..31: mean over heads at d=l
  if (l < DK) {
    float acc = 0.f;
#pragma unroll
    for (int d = 0; d < DK; ++d) acc += __shfl(hbar, d) * msgwf[l * DK + d];
    msgb[(size_t)n * DK + l] = acc;
  }
}

// ---- K3: per-edge logits + LeakyReLU + per-head global max -------------------
__global__ __launch_bounds__(256) void k_logits(const int* __restrict__ src,
                                                const int* __restrict__ dst,
                                                const void* __restrict__ sim1,
                                                const int* __restrict__ dflag,
                                                const float* __restrict__ s_src,
                                                const float* __restrict__ s_dst,
                                                float4* __restrict__ e_vals,
                                                unsigned* __restrict__ gmax, int E) {
  const int e = blockIdx.x * 256 + threadIdx.x;
  float m0 = -FLT_MAX, m1 = -FLT_MAX, m2 = -FLT_MAX, m3 = -FLT_MAX;
  if (e < E) {
    int s = src[e], d = dst[e];
    float4 ss = *(const float4*)(s_src + (size_t)s * 4);
    float4 sd = *(const float4*)(s_dst + (size_t)d * 4);
    float sv = (*dflag) ? ((const float*)sim1)[e] : bf2f(((const unsigned short*)sim1)[e]);
    float b = kBeta * sv;
    float e0 = ss.x + sd.x + b; e0 = (e0 >= 0.f) ? e0 : kNeg * e0;
    float e1 = ss.y + sd.y + b; e1 = (e1 >= 0.f) ? e1 : kNeg * e1;
    float e2 = ss.z + sd.z + b; e2 = (e2 >= 0.f) ? e2 : kNeg * e2;
    float e3 = ss.w + sd.w + b; e3 = (e3 >= 0.f) ? e3 : kNeg * e3;
    e_vals[e] = make_float4(e0, e1, e2, e3);
    m0 = e0; m1 = e1; m2 = e2; m3 = e3;
  }
#pragma unroll
  for (int off = 32; off; off >>= 1) {
    m0 = fmaxf(m0, __shfl_xor(m0, off));
    m1 = fmaxf(m1, __shfl_xor(m1, off));
    m2 = fmaxf(m2, __shfl_xor(m2, off));
    m3 = fmaxf(m3, __shfl_xor(m3, off));
  }
  __shared__ float red[4][4];
  if ((threadIdx.x & 63) == 0) {
    int w = threadIdx.x >> 6;
    red[w][0] = m0; red[w][1] = m1; red[w][2] = m2; red[w][3] = m3;
  }
  __syncthreads();
  if (threadIdx.x < 4) {
    int h = threadIdx.x;
    float mm = fmaxf(fmaxf(red[0][h], red[1][h]), fmaxf(red[2][h], red[3][h]));
    atomicMax(gmax + h, fkey(mm));
  }
}

// ---- K4: msg_base gather (coalesced writes) ----------------------------------
__global__ __launch_bounds__(256) void k_msg(const int* __restrict__ src,
                                             const float* __restrict__ msgb,
                                             const int* __restrict__ dflag,
                                             void* __restrict__ d_out,
                                             int N, int E) {
  long long tid = (long long)blockIdx.x * 256 + threadIdx.x;
  if (tid >= (long long)E * DK) return;
  int e = (int)(tid >> 5), j = (int)(tid & 31);
  float mv = msgb[(size_t)src[e] * DK + j];
  const size_t msg_off = (size_t)N * 128 + (size_t)E;
  if (*dflag) ((float*)d_out)[msg_off + (size_t)e * DK + j] = mv;
  else        ((__hip_bfloat16*)d_out)[msg_off + (size_t)e * DK + j] = __float2bfloat16(mv);
}

// ---- K5: wave-per-node CSR gather: exp, denom, alpha_mean, out_h -------------
__global__ __launch_bounds__(256) void k_out(const int* __restrict__ row_ptr,
                                             const int* __restrict__ eidx,
                                             const int* __restrict__ src,
                                             const float4* __restrict__ e_vals,
                                             const unsigned* __restrict__ gmax,
                                             const float* __restrict__ Hproj,
                                             const int* __restrict__ dflag,
                                             void* __restrict__ d_out, int N, int E) {
  const int n = (int)((blockIdx.x * 256 + threadIdx.x) >> 6);
  const int l = threadIdx.x & 63;
  if (n >= N) return;
  const int beg = row_ptr[n];
  const int deg = row_ptr[n + 1] - beg;
  const int dt = *dflag;
  const float m0 = funkey(gmax[0]), m1 = funkey(gmax[1]);
  const float m2 = funkey(gmax[2]), m3 = funkey(gmax[3]);
  const size_t alpha_off = (size_t)N * 128;
  float acc_lo = 0.f, acc_hi = 0.f;
  float4 dn = make_float4(0.f, 0.f, 0.f, 0.f);
  int eid = 0, s = 0;
  float4 ev = make_float4(0.f, 0.f, 0.f, 0.f);
  const bool small = (deg <= 64);
  if (small) {
    if (l < deg) {
      eid = eidx[beg + l];
      float4 r = e_vals[eid];
      ev = make_float4(expf(r.x - m0), expf(r.y - m1),
                       expf(r.z - m2), expf(r.w - m3));
      s = src[eid];
      dn = ev;
    }
  } else {
    for (int base = 0; base < deg; base += 64) {
      if (base + l < deg) {
        int e2 = eidx[beg + base + l];
        float4 r = e_vals[e2];
        dn.x += expf(r.x - m0); dn.y += expf(r.y - m1);
        dn.z += expf(r.z - m2); dn.w += expf(r.w - m3);
      }
    }
  }
#pragma unroll
  for (int off = 32; off; off >>= 1) {
    dn.x += __shfl_xor(dn.x, off);
    dn.y += __shfl_xor(dn.y, off);
    dn.z += __shfl_xor(dn.z, off);
    dn.w += __shfl_xor(dn.w, off);
  }
  const float i0 = 1.f / (dn.x + kEps), i1 = 1.f / (dn.y + kEps);
  const float i2 = 1.f / (dn.z + kEps), i3 = 1.f / (dn.w + kEps);
  if (small) {
    if (l < deg) {
      float am = 0.25f * (ev.x * i0 + ev.y * i1 + ev.z * i2 + ev.w * i3);
      if (dt) ((float*)d_out)[alpha_off + eid] = am;
      else    ((__hip_bfloat16*)d_out)[alpha_off + eid] = __float2bfloat16(am);
    }
    for (int i = 0; i < deg; ++i) {
      int si = __shfl(s, i);
      float ax = __shfl(ev.x, i), ay = __shfl(ev.y, i);
      float az = __shfl(ev.z, i), aw = __shfl(ev.w, i);
      float a_lo = (l < 32) ? ax * i0 : ay * i1;
      float a_hi = (l < 32) ? az * i2 : aw * i3;
      acc_lo += a_lo * Hproj[(size_t)si * 128 + l];
      acc_hi += a_hi * Hproj[(size_t)si * 128 + 64 + l];
    }
  } else {
    for (int base = 0; base < deg; base += 64) {
      int cnt = min(64, deg - base);
      int eid2 = 0, s2 = 0;
      float4 e2 = make_float4(0.f, 0.f, 0.f, 0.f);
      if (l < cnt) {
        eid2 = eidx[beg + base + l];
        float4 r = e_vals[eid2];
        e2 = make_float4(expf(r.x - m0), expf(r.y - m1),
                         expf(r.z - m2), expf(r.w - m3));
        s2 = src[eid2];
        float am = 0.25f * (e2.x * i0 + e2.y * i1 + e2.z * i2 + e2.w * i3);
        if (dt) ((float*)d_out)[alpha_off + eid2] = am;
        else    ((__hip_bfloat16*)d_out)[alpha_off + eid2] = __float2bfloat16(am);
      }
      for (int i = 0; i < cnt; ++i) {
        int si = __shfl(s2, i);
        float ax = __shfl(e2.x, i), ay = __shfl(e2.y, i);
        float az = __shfl(e2.z, i), aw = __shfl(e2.w, i);
        float a_lo = (l < 32) ? ax * i0 : ay * i1;
        float a_hi = (l < 32) ? az * i2 : aw * i3;
        acc_lo += a_lo * Hproj[(size_t)si * 128 + l];
        acc_hi += a_hi * Hproj[(size_t)si * 128 + 64 + l];
      }
    }
  }
  if (dt) {
    ((float*)d_out)[(size_t)n * 128 + l]      = acc_lo;
    ((float*)d_out)[(size_t)n * 128 + 64 + l] = acc_hi;
  } else {
    ((__hip_bfloat16*)d_out)[(size_t)n * 128 + l]      = __float2bfloat16(acc_lo);
    ((__hip_bfloat16*)d_out)[(size_t)n * 128 + 64 + l] = __float2bfloat16(acc_hi);
  }
}

extern "C" void kernel_launch(void* const* d_in, const int* in_sizes, int n_in,
                              void* d_out, int out_size, void* d_ws, size_t ws_size,
                              hipStream_t stream) {
  const void* H     = d_in[0];
  const int*  ei    = (const int*)d_in[1];
  const void* sim1  = d_in[2];
  const void* W     = d_in[3];
  const void* a_src = d_in[4];
  const void* a_dst = d_in[5];
  const void* msg_w = d_in[6];
  const int N = in_sizes[0] / 256;
  const int E = in_sizes[2];

  float* ws      = (float*)d_ws;
  float* Hproj   = ws;                           // N*128
  float* s_src   = Hproj  + (size_t)N * 128;     // N*4
  float* s_dst   = s_src  + (size_t)N * 4;       // N*4
  float* msgb    = s_dst  + (size_t)N * 4;       // N*32
  float* e_vals  = msgb   + (size_t)N * 32;      // E*4
  int* deg       = (int*)(e_vals + (size_t)E * 4);  // N   <- zeroed from here
  unsigned* gmax = (unsigned*)(deg + N);         // 4
  int* eflag     = (int*)(gmax + 4);             // 1
  int* dflag     = eflag + 1;                    // 1   <- zeroed to here
  int* row_ptr   = dflag + 1;                    // N+1
  int* cursor    = row_ptr + N + 1;              // N
  int* eidx      = cursor + N;                   // E
  int* src_i     = eidx + E;                     // E
  int* dst_i     = src_i + E;                    // E
  float* Wf      = (float*)(dst_i + E);          // 128*256
  float* af      = Wf + 128 * 256;               // 256: [a_src|a_dst]
  float* msgwf   = af + 256;                     // 1024

  hipMemsetAsync(deg, 0, (size_t)(N + 6) * sizeof(int), stream);

  k_detect_edges<<<16, 256, 0, stream>>>(ei, eflag, E);
  k_detect_dtype<<<512, 256, 0, stream>>>((const unsigned*)H, dflag, 131072);
  k_cvt<<<(E + 255) / 256, 256, 0, stream>>>(ei, eflag, src_i, dst_i, deg, E);
  k_f32cvt<<<128, 256, 0, stream>>>(W, Wf, dflag, 128 * 256);
  k_f32cvt<<<1, 256, 0, stream>>>(a_src, af, dflag, 128);
  k_f32cvt<<<1, 256, 0, stream>>>(a_dst, af + 128, dflag, 128);
  k_f32cvt<<<4, 256, 0, stream>>>(msg_w, msgwf, dflag, 1024);
  k_proj<<<(N + 31) / 32, 256, 0, stream>>>(H, Wf, dflag, Hproj, N);
  k_scan<<<1, 1024, 0, stream>>>(deg, row_ptr, cursor, N);
  k_fill<<<(E + 255) / 256, 256, 0, stream>>>(dst_i, cursor, eidx, E);
  k_node<<<(N + 3) / 4, 256, 0, stream>>>(Hproj, af, msgwf, s_src, s_dst, msgb, N);
  k_logits<<<(E + 255) / 256, 256, 0, stream>>>(src_i, dst_i, sim1, dflag, s_src, s_dst,
                                                (float4*)e_vals, gmax, E);
  k_msg<<<(int)(((long long)E * DK + 255) / 256), 256, 0, stream>>>(src_i, msgb, dflag,
                                                                    d_out, N, E);
  k_out<<<(int)(((size_t)N * 64 + 255) / 256), 256, 0, stream>>>(
      row_ptr, eidx, src_i, (const float4*)e_vals, gmax, Hproj, dflag, d_out, N, E);
}

// Round 2
// 662.504 us; speedup vs baseline: 1.5008x; 1.2058x over previous
//
#include <hip/hip_runtime.h>
#include <hip/hip_bf16.h>
#include <float.h>

#define HEADS 4
#define DK 32

static constexpr float kBeta = 1.0f;
static constexpr float kNeg  = 0.2f;
static constexpr float kEps  = 1e-12f;

__device__ __forceinline__ float bf2f(unsigned short v) {
  return __uint_as_float((unsigned)v << 16);
}
__device__ __forceinline__ float2 bfp2(unsigned u) {
  return make_float2(__uint_as_float(u << 16), __uint_as_float(u & 0xFFFF0000u));
}
// order-preserving float <-> uint key for atomicMax
__device__ __forceinline__ unsigned fkey(float x) {
  unsigned u = __float_as_uint(x);
  return (u & 0x80000000u) ? ~u : (u | 0x80000000u);
}
__device__ __forceinline__ float funkey(unsigned k) {
  unsigned u = (k & 0x80000000u) ? (k & 0x7fffffffu) : ~k;
  return __uint_as_float(u);
}

// ---- K0a: edge layout detect (int64 -> odd words all 0) ----------------------
__global__ __launch_bounds__(256) void k_detect_edges(const int* __restrict__ ei32,
                                                      int* __restrict__ eflag, int E) {
  int i = blockIdx.x * 256 + threadIdx.x;  // [0, 4096)
  if (2 * i + 1 < 2 * E && ei32[2 * i + 1] != 0) atomicOr(eflag, 1);
}

// ---- K0b: float dtype detect: fp32 words have random mantissa bits 14..7 -----
__global__ __launch_bounds__(256) void k_detect_dtype(const unsigned* __restrict__ Hw,
                                                      int* __restrict__ dflag, int nw) {
  int i = blockIdx.x * 256 + threadIdx.x;
  if (i < nw && ((Hw[i] >> 7) & 0xFFu) == 0xFFu) atomicOr(dflag, 1);
}

// ---- K0c: normalize edge index into int32 src/dst + degree histogram ---------
__global__ __launch_bounds__(256) void k_cvt(const int* __restrict__ ei32,
                                             const int* __restrict__ eflag,
                                             int* __restrict__ src_i,
                                             int* __restrict__ dst_i,
                                             int* __restrict__ deg, int E) {
  int i = blockIdx.x * 256 + threadIdx.x;
  if (i >= E) return;
  int s, d;
  if (*eflag) { s = ei32[i];     d = ei32[E + i]; }
  else        { s = ei32[2 * i]; d = ei32[2 * E + 2 * i]; }
  src_i[i] = s;
  dst_i[i] = d;
  atomicAdd(deg + d, 1);
}

// ---- K0d: param convert to fp32 (identity copy if already fp32) --------------
__global__ __launch_bounds__(256) void k_f32cvt(const void* __restrict__ in,
                                                float* __restrict__ out,
                                                const int* __restrict__ dflag, int n) {
  int i = blockIdx.x * 256 + threadIdx.x;
  if (i >= n) return;
  out[i] = (*dflag) ? ((const float*)in)[i] : bf2f(((const unsigned short*)in)[i]);
}

// ---- K0d': W convert + transpose: Wt[k][out] = W[out][k] ---------------------
__global__ __launch_bounds__(256) void k_wcvt(const void* __restrict__ in,
                                              float* __restrict__ out,
                                              const int* __restrict__ dflag, int n) {
  int i = blockIdx.x * 256 + threadIdx.x;  // i = r*256 + c, r: out-row, c: k
  if (i >= n) return;
  int r = i >> 8, c = i & 255;
  float v = (*dflag) ? ((const float*)in)[i] : bf2f(((const unsigned short*)in)[i]);
  out[(size_t)c * 128 + r] = v;
}

// ---- K0e: exclusive scan of deg -> row_ptr, cursor (single block) ------------
__global__ __launch_bounds__(1024) void k_scan(const int* __restrict__ deg,
                                               int* __restrict__ row_ptr,
                                               int* __restrict__ cursor, int N) {
  __shared__ int part[1024];
  const int t = threadIdx.x;
  const int C = (N + 1023) >> 10;
  const int b = t * C;
  int s = 0;
  for (int i = 0; i < C; ++i) {
    int idx = b + i;
    if (idx < N) s += deg[idx];
  }
  part[t] = s;
  __syncthreads();
  for (int off = 1; off < 1024; off <<= 1) {
    int v = (t >= off) ? part[t - off] : 0;
    __syncthreads();
    part[t] += v;
    __syncthreads();
  }
  int run = (t == 0) ? 0 : part[t - 1];
  for (int i = 0; i < C; ++i) {
    int idx = b + i;
    if (idx < N) {
      row_ptr[idx] = run;
      cursor[idx] = run;
      run += deg[idx];
    }
  }
  if (t == 1023) row_ptr[N] = part[1023];
}

// ---- K0f: fill CSR edge lists ------------------------------------------------
__global__ __launch_bounds__(256) void k_fill(const int* __restrict__ dst,
                                              int* __restrict__ cursor,
                                              int* __restrict__ eidx, int E) {
  int e = blockIdx.x * 256 + threadIdx.x;
  if (e >= E) return;
  int pos = atomicAdd(cursor + dst[e], 1);
  eidx[pos] = e;
}

// ---- K1: H_proj = H @ W.T (W pre-transposed to Wt[k][out], coalesced) --------
__global__ __launch_bounds__(256) void k_proj(const void* __restrict__ Hraw,
                                              const float* __restrict__ Wtf,
                                              const int* __restrict__ dflag,
                                              float* __restrict__ Hproj, int N) {
  __shared__ float Ht[32][260];
  const int t = threadIdx.x;
  const int nb = blockIdx.x * 32;
  const int dt = *dflag;
  if (dt) {  // fp32 input
    const float4* __restrict__ H4 = (const float4*)Hraw;
#pragma unroll
    for (int i = 0; i < 8; ++i) {
      int f = t + i * 256;
      int r = f >> 6, kq = f & 63;
      float4 v = make_float4(0.f, 0.f, 0.f, 0.f);
      if (nb + r < N) v = H4[(size_t)(nb + r) * 64 + kq];
      *(float4*)&Ht[r][4 * kq] = v;
    }
  } else {   // bf16 input
    const uint4* __restrict__ H8 = (const uint4*)Hraw;
#pragma unroll
    for (int i = 0; i < 4; ++i) {
      int g = t + i * 256;
      int r = g >> 5, c8 = g & 31;
      uint4 v = make_uint4(0u, 0u, 0u, 0u);
      if (nb + r < N) v = H8[(size_t)(nb + r) * 32 + c8];
      float2 f0 = bfp2(v.x), f1 = bfp2(v.y), f2 = bfp2(v.z), f3 = bfp2(v.w);
      *(float4*)&Ht[r][c8 * 8 + 0] = make_float4(f0.x, f0.y, f1.x, f1.y);
      *(float4*)&Ht[r][c8 * 8 + 4] = make_float4(f2.x, f2.y, f3.x, f3.y);
    }
  }
  __syncthreads();
  const int cg = (t & 31);          // col-group: cols 4*cg .. 4*cg+3
  const int n0 = (t >> 5) * 4;
  float acc[4][4];
#pragma unroll
  for (int n = 0; n < 4; ++n)
#pragma unroll
    for (int j = 0; j < 4; ++j) acc[n][j] = 0.f;
  const float4* __restrict__ Wt4 = (const float4*)Wtf;  // [256][32] float4
#pragma unroll 4
  for (int kk = 0; kk < 256; kk += 4) {
    float4 w0 = Wt4[(size_t)(kk + 0) * 32 + cg];
    float4 w1 = Wt4[(size_t)(kk + 1) * 32 + cg];
    float4 w2 = Wt4[(size_t)(kk + 2) * 32 + cg];
    float4 w3 = Wt4[(size_t)(kk + 3) * 32 + cg];
#pragma unroll
    for (int n = 0; n < 4; ++n) {
      float4 h = *(const float4*)&Ht[n0 + n][kk];
      acc[n][0] += h.x * w0.x + h.y * w1.x + h.z * w2.x + h.w * w3.x;
      acc[n][1] += h.x * w0.y + h.y * w1.y + h.z * w2.y + h.w * w3.y;
      acc[n][2] += h.x * w0.z + h.y * w1.z + h.z * w2.z + h.w * w3.z;
      acc[n][3] += h.x * w0.w + h.y * w1.w + h.z * w2.w + h.w * w3.w;
    }
  }
#pragma unroll
  for (int n = 0; n < 4; ++n) {
    int row = nb + n0 + n;
    if (row < N)
      *(float4*)&Hproj[(size_t)row * 128 + 4 * cg] =
          make_float4(acc[n][0], acc[n][1], acc[n][2], acc[n][3]);
  }
}

// ---- K2: per-node attention dots + msg base ----------------------------------
__global__ __launch_bounds__(256) void k_node(const float* __restrict__ Hproj,
                                              const float* __restrict__ af,   // [a_src(128)|a_dst(128)]
                                              const float* __restrict__ msgwf,
                                              float* __restrict__ s_src,
                                              float* __restrict__ s_dst,
                                              float* __restrict__ msgb, int N) {
  const int l = threadIdx.x & 63;
  const int wb = threadIdx.x >> 6;
  const int n = (blockIdx.x << 2) + wb;
  if (n >= N) return;
  const float* row = Hproj + (size_t)n * 128;
  float h0 = row[l], h1 = row[64 + l];
  float p0 = h0 * af[l],       p1 = h1 * af[64 + l];
  float q0 = h0 * af[128 + l], q1 = h1 * af[192 + l];
#pragma unroll
  for (int off = 16; off; off >>= 1) {
    p0 += __shfl_xor(p0, off);
    p1 += __shfl_xor(p1, off);
    q0 += __shfl_xor(q0, off);
    q1 += __shfl_xor(q1, off);
  }
  if (l == 0)  { s_src[n*4+0] = p0; s_src[n*4+2] = p1; s_dst[n*4+0] = q0; s_dst[n*4+2] = q1; }
  if (l == 32) { s_src[n*4+1] = p0; s_src[n*4+3] = p1; s_dst[n*4+1] = q0; s_dst[n*4+3] = q1; }
  float t4 = h0 + __shfl_xor(h0, 32) + h1 + __shfl_xor(h1, 32);
  float hbar = 0.25f * t4;  // lanes 0..31: mean over heads at d=l
  if (l < DK) {
    float acc = 0.f;
#pragma unroll
    for (int d = 0; d < DK; ++d) acc += __shfl(hbar, d) * msgwf[l * DK + d];
    msgb[(size_t)n * DK + l] = acc;
  }
}

// ---- K3: per-edge logits + LeakyReLU + per-head global max -------------------
__global__ __launch_bounds__(256) void k_logits(const int* __restrict__ src,
                                                const int* __restrict__ dst,
                                                const void* __restrict__ sim1,
                                                const int* __restrict__ dflag,
                                                const float* __restrict__ s_src,
                                                const float* __restrict__ s_dst,
                                                float4* __restrict__ e_vals,
                                                unsigned* __restrict__ gmax, int E) {
  const int e = blockIdx.x * 256 + threadIdx.x;
  float m0 = -FLT_MAX, m1 = -FLT_MAX, m2 = -FLT_MAX, m3 = -FLT_MAX;
  if (e < E) {
    int s = src[e], d = dst[e];
    float4 ss = *(const float4*)(s_src + (size_t)s * 4);
    float4 sd = *(const float4*)(s_dst + (size_t)d * 4);
    float sv = (*dflag) ? ((const float*)sim1)[e] : bf2f(((const unsigned short*)sim1)[e]);
    float b = kBeta * sv;
    float e0 = ss.x + sd.x + b; e0 = (e0 >= 0.f) ? e0 : kNeg * e0;
    float e1 = ss.y + sd.y + b; e1 = (e1 >= 0.f) ? e1 : kNeg * e1;
    float e2 = ss.z + sd.z + b; e2 = (e2 >= 0.f) ? e2 : kNeg * e2;
    float e3 = ss.w + sd.w + b; e3 = (e3 >= 0.f) ? e3 : kNeg * e3;
    e_vals[e] = make_float4(e0, e1, e2, e3);
    m0 = e0; m1 = e1; m2 = e2; m3 = e3;
  }
#pragma unroll
  for (int off = 32; off; off >>= 1) {
    m0 = fmaxf(m0, __shfl_xor(m0, off));
    m1 = fmaxf(m1, __shfl_xor(m1, off));
    m2 = fmaxf(m2, __shfl_xor(m2, off));
    m3 = fmaxf(m3, __shfl_xor(m3, off));
  }
  __shared__ float red[4][4];
  if ((threadIdx.x & 63) == 0) {
    int w = threadIdx.x >> 6;
    red[w][0] = m0; red[w][1] = m1; red[w][2] = m2; red[w][3] = m3;
  }
  __syncthreads();
  if (threadIdx.x < 4) {
    int h = threadIdx.x;
    float mm = fmaxf(fmaxf(red[0][h], red[1][h]), fmaxf(red[2][h], red[3][h]));
    atomicMax(gmax + h, fkey(mm));
  }
}

// ---- K4: msg_base gather (coalesced writes) ----------------------------------
__global__ __launch_bounds__(256) void k_msg(const int* __restrict__ src,
                                             const float* __restrict__ msgb,
                                             const int* __restrict__ dflag,
                                             void* __restrict__ d_out,
                                             int N, int E) {
  long long tid = (long long)blockIdx.x * 256 + threadIdx.x;
  if (tid >= (long long)E * DK) return;
  int e = (int)(tid >> 5), j = (int)(tid & 31);
  float mv = msgb[(size_t)src[e] * DK + j];
  const size_t msg_off = (size_t)N * 128 + (size_t)E;
  if (*dflag) ((float*)d_out)[msg_off + (size_t)e * DK + j] = mv;
  else        ((__hip_bfloat16*)d_out)[msg_off + (size_t)e * DK + j] = __float2bfloat16(mv);
}

// ---- K5: wave-per-node CSR gather: exp, denom, alpha_mean, out_h -------------
__global__ __launch_bounds__(256) void k_out(const int* __restrict__ row_ptr,
                                             const int* __restrict__ eidx,
                                             const int* __restrict__ src,
                                             const float4* __restrict__ e_vals,
                                             const unsigned* __restrict__ gmax,
                                             const float* __restrict__ Hproj,
                                             const int* __restrict__ dflag,
                                             void* __restrict__ d_out, int N, int E) {
  const int n = (int)((blockIdx.x * 256 + threadIdx.x) >> 6);
  const int l = threadIdx.x & 63;
  if (n >= N) return;
  const int beg = row_ptr[n];
  const int deg = row_ptr[n + 1] - beg;
  const int dt = *dflag;
  const float m0 = funkey(gmax[0]), m1 = funkey(gmax[1]);
  const float m2 = funkey(gmax[2]), m3 = funkey(gmax[3]);
  const size_t alpha_off = (size_t)N * 128;
  float acc_lo = 0.f, acc_hi = 0.f;
  float4 dn = make_float4(0.f, 0.f, 0.f, 0.f);
  int eid = 0, s = 0;
  float4 ev = make_float4(0.f, 0.f, 0.f, 0.f);
  const bool small = (deg <= 64);
  if (small) {
    if (l < deg) {
      eid = eidx[beg + l];
      float4 r = e_vals[eid];
      ev = make_float4(expf(r.x - m0), expf(r.y - m1),
                       expf(r.z - m2), expf(r.w - m3));
      s = src[eid];
      dn = ev;
    }
  } else {
    for (int base = 0; base < deg; base += 64) {
      if (base + l < deg) {
        int e2 = eidx[beg + base + l];
        float4 r = e_vals[e2];
        dn.x += expf(r.x - m0); dn.y += expf(r.y - m1);
        dn.z += expf(r.z - m2); dn.w += expf(r.w - m3);
      }
    }
  }
#pragma unroll
  for (int off = 32; off; off >>= 1) {
    dn.x += __shfl_xor(dn.x, off);
    dn.y += __shfl_xor(dn.y, off);
    dn.z += __shfl_xor(dn.z, off);
    dn.w += __shfl_xor(dn.w, off);
  }
  const float i0 = 1.f / (dn.x + kEps), i1 = 1.f / (dn.y + kEps);
  const float i2 = 1.f / (dn.z + kEps), i3 = 1.f / (dn.w + kEps);
  if (small) {
    if (l < deg) {
      float am = 0.25f * (ev.x * i0 + ev.y * i1 + ev.z * i2 + ev.w * i3);
      if (dt) ((float*)d_out)[alpha_off + eid] = am;
      else    ((__hip_bfloat16*)d_out)[alpha_off + eid] = __float2bfloat16(am);
    }
    for (int i = 0; i < deg; ++i) {
      int si = __shfl(s, i);
      float ax = __shfl(ev.x, i), ay = __shfl(ev.y, i);
      float az = __shfl(ev.z, i), aw = __shfl(ev.w, i);
      float a_lo = (l < 32) ? ax * i0 : ay * i1;
      float a_hi = (l < 32) ? az * i2 : aw * i3;
      acc_lo += a_lo * Hproj[(size_t)si * 128 + l];
      acc_hi += a_hi * Hproj[(size_t)si * 128 + 64 + l];
    }
  } else {
    for (int base = 0; base < deg; base += 64) {
      int cnt = min(64, deg - base);
      int eid2 = 0, s2 = 0;
      float4 e2 = make_float4(0.f, 0.f, 0.f, 0.f);
      if (l < cnt) {
        eid2 = eidx[beg + base + l];
        float4 r = e_vals[eid2];
        e2 = make_float4(expf(r.x - m0), expf(r.y - m1),
                         expf(r.z - m2), expf(r.w - m3));
        s2 = src[eid2];
        float am = 0.25f * (e2.x * i0 + e2.y * i1 + e2.z * i2 + e2.w * i3);
        if (dt) ((float*)d_out)[alpha_off + eid2] = am;
        else    ((__hip_bfloat16*)d_out)[alpha_off + eid2] = __float2bfloat16(am);
      }
      for (int i = 0; i < cnt; ++i) {
        int si = __shfl(s2, i);
        float ax = __shfl(e2.x, i), ay = __shfl(e2.y, i);
        float az = __shfl(e2.z, i), aw = __shfl(e2.w, i);
        float a_lo = (l < 32) ? ax * i0 : ay * i1;
        float a_hi = (l < 32) ? az * i2 : aw * i3;
        acc_lo += a_lo * Hproj[(size_t)si * 128 + l];
        acc_hi += a_hi * Hproj[(size_t)si * 128 + 64 + l];
      }
    }
  }
  if (dt) {
    ((float*)d_out)[(size_t)n * 128 + l]      = acc_lo;
    ((float*)d_out)[(size_t)n * 128 + 64 + l] = acc_hi;
  } else {
    ((__hip_bfloat16*)d_out)[(size_t)n * 128 + l]      = __float2bfloat16(acc_lo);
    ((__hip_bfloat16*)d_out)[(size_t)n * 128 + 64 + l] = __float2bfloat16(acc_hi);
  }
}

extern "C" void kernel_launch(void* const* d_in, const int* in_sizes, int n_in,
                              void* d_out, int out_size, void* d_ws, size_t ws_size,
                              hipStream_t stream) {
  const void* H     = d_in[0];
  const int*  ei    = (const int*)d_in[1];
  const void* sim1  = d_in[2];
  const void* W     = d_in[3];
  const void* a_src = d_in[4];
  const void* a_dst = d_in[5];
  const void* msg_w = d_in[6];
  const int N = in_sizes[0] / 256;
  const int E = in_sizes[2];

  float* ws      = (float*)d_ws;
  float* Hproj   = ws;                           // N*128
  float* s_src   = Hproj  + (size_t)N * 128;     // N*4
  float* s_dst   = s_src  + (size_t)N * 4;       // N*4
  float* msgb    = s_dst  + (size_t)N * 4;       // N*32
  float* e_vals  = msgb   + (size_t)N * 32;      // E*4
  int* deg       = (int*)(e_vals + (size_t)E * 4);  // N   <- zeroed from here
  unsigned* gmax = (unsigned*)(deg + N);         // 4
  int* eflag     = (int*)(gmax + 4);             // 1
  int* dflag     = eflag + 1;                    // 1   <- zeroed to here
  int* row_ptr   = dflag + 1;                    // N+1
  int* cursor    = row_ptr + N + 1;              // N
  int* eidx      = cursor + N;                   // E
  int* src_i     = eidx + E;                     // E
  int* dst_i     = src_i + E;                    // E
  float* Wtf     = (float*)(dst_i + E);          // 256*128 (transposed W)
  float* af      = Wtf + 128 * 256;              // 256: [a_src|a_dst]
  float* msgwf   = af + 256;                     // 1024

  hipMemsetAsync(deg, 0, (size_t)(N + 6) * sizeof(int), stream);

  k_detect_edges<<<16, 256, 0, stream>>>(ei, eflag, E);
  k_detect_dtype<<<512, 256, 0, stream>>>((const unsigned*)H, dflag, 131072);
  k_cvt<<<(E + 255) / 256, 256, 0, stream>>>(ei, eflag, src_i, dst_i, deg, E);
  k_wcvt<<<128, 256, 0, stream>>>(W, Wtf, dflag, 128 * 256);
  k_f32cvt<<<1, 256, 0, stream>>>(a_src, af, dflag, 128);
  k_f32cvt<<<1, 256, 0, stream>>>(a_dst, af + 128, dflag, 128);
  k_f32cvt<<<4, 256, 0, stream>>>(msg_w, msgwf, dflag, 1024);
  k_proj<<<(N + 31) / 32, 256, 0, stream>>>(H, Wtf, dflag, Hproj, N);
  k_scan<<<1, 1024, 0, stream>>>(deg, row_ptr, cursor, N);
  k_fill<<<(E + 255) / 256, 256, 0, stream>>>(dst_i, cursor, eidx, E);
  k_node<<<(N + 3) / 4, 256, 0, stream>>>(Hproj, af, msgwf, s_src, s_dst, msgb, N);
  k_logits<<<(E + 255) / 256, 256, 0, stream>>>(src_i, dst_i, sim1, dflag, s_src, s_dst,
                                                (float4*)e_vals, gmax, E);
  k_msg<<<(int)(((long long)E * DK + 255) / 256), 256, 0, stream>>>(src_i, msgb, dflag,
                                                                    d_out, N, E);
  k_out<<<(int)(((size_t)N * 64 + 255) / 256), 256, 0, stream>>>(
      row_ptr, eidx, src_i, (const float4*)e_vals, gmax, Hproj, dflag, d_out, N, E);
}

// Round 3
// 544.154 us; speedup vs baseline: 1.8272x; 1.2175x over previous
//
#include <hip/hip_runtime.h>
#include <hip/hip_bf16.h>
#include <float.h>

#define HEADS 4
#define DK 32

static constexpr float kBeta = 1.0f;
static constexpr float kNeg  = 0.2f;
static constexpr float kEps  = 1e-12f;

__device__ __forceinline__ float bf2f(unsigned short v) {
  return __uint_as_float((unsigned)v << 16);
}
__device__ __forceinline__ float2 bfp2(unsigned u) {
  return make_float2(__uint_as_float(u << 16), __uint_as_float(u & 0xFFFF0000u));
}
// order-preserving float <-> uint key for atomicMax
__device__ __forceinline__ unsigned fkey(float x) {
  unsigned u = __float_as_uint(x);
  return (u & 0x80000000u) ? ~u : (u | 0x80000000u);
}
__device__ __forceinline__ float funkey(unsigned k) {
  unsigned u = (k & 0x80000000u) ? (k & 0x7fffffffu) : ~k;
  return __uint_as_float(u);
}

// ---- K0a: edge layout detect (int64 -> odd words all 0) ----------------------
__global__ __launch_bounds__(256) void k_detect_edges(const int* __restrict__ ei32,
                                                      int* __restrict__ eflag, int E) {
  int i = blockIdx.x * 256 + threadIdx.x;  // [0, 4096)
  if (2 * i + 1 < 2 * E && ei32[2 * i + 1] != 0) atomicOr(eflag, 1);
}

// ---- K0b: float dtype detect: fp32 words have random mantissa bits 14..7 -----
__global__ __launch_bounds__(256) void k_detect_dtype(const unsigned* __restrict__ Hw,
                                                      int* __restrict__ dflag, int nw) {
  int i = blockIdx.x * 256 + threadIdx.x;
  if (i < nw && ((Hw[i] >> 7) & 0xFFu) == 0xFFu) atomicOr(dflag, 1);
}

// ---- K0c: normalize edge index into int32 src/dst + degree histogram ---------
__global__ __launch_bounds__(256) void k_cvt(const int* __restrict__ ei32,
                                             const int* __restrict__ eflag,
                                             int* __restrict__ src_i,
                                             int* __restrict__ dst_i,
                                             int* __restrict__ deg, int E) {
  int i = blockIdx.x * 256 + threadIdx.x;
  if (i >= E) return;
  int s, d;
  if (*eflag) { s = ei32[i];     d = ei32[E + i]; }
  else        { s = ei32[2 * i]; d = ei32[2 * E + 2 * i]; }
  src_i[i] = s;
  dst_i[i] = d;
  atomicAdd(deg + d, 1);
}

// ---- K0d: param convert to fp32 (identity copy if already fp32) --------------
__global__ __launch_bounds__(256) void k_f32cvt(const void* __restrict__ in,
                                                float* __restrict__ out,
                                                const int* __restrict__ dflag, int n) {
  int i = blockIdx.x * 256 + threadIdx.x;
  if (i >= n) return;
  out[i] = (*dflag) ? ((const float*)in)[i] : bf2f(((const unsigned short*)in)[i]);
}

// ---- K0d': W convert + transpose: Wt[k][out] = W[out][k] ---------------------
__global__ __launch_bounds__(256) void k_wcvt(const void* __restrict__ in,
                                              float* __restrict__ out,
                                              const int* __restrict__ dflag, int n) {
  int i = blockIdx.x * 256 + threadIdx.x;  // i = r*256 + c, r: out-row, c: k
  if (i >= n) return;
  int r = i >> 8, c = i & 255;
  float v = (*dflag) ? ((const float*)in)[i] : bf2f(((const unsigned short*)in)[i]);
  out[(size_t)c * 128 + r] = v;
}

// ---- K0e: 3-phase device-wide exclusive scan of deg --------------------------
// phase 1: per-block (256 elems) sums
__global__ __launch_bounds__(256) void k_scan1(const int* __restrict__ deg,
                                               int* __restrict__ bsum, int N) {
  const int t = threadIdx.x;
  int i = blockIdx.x * 256 + t;
  int v = (i < N) ? deg[i] : 0;
#pragma unroll
  for (int off = 32; off; off >>= 1) v += __shfl_xor(v, off);
  __shared__ int red[4];
  if ((t & 63) == 0) red[t >> 6] = v;
  __syncthreads();
  if (t == 0) bsum[blockIdx.x] = red[0] + red[1] + red[2] + red[3];
}
// phase 2: scan block sums (single block, up to 1024 partials)
__global__ __launch_bounds__(1024) void k_scan2(int* __restrict__ bsum, int nb) {
  __shared__ int part[1024];
  const int t = threadIdx.x;
  part[t] = (t < nb) ? bsum[t] : 0;
  __syncthreads();
  int own = part[t];
  for (int off = 1; off < 1024; off <<= 1) {
    int v = (t >= off) ? part[t - off] : 0;
    __syncthreads();
    part[t] += v;
    __syncthreads();
  }
  if (t < nb) bsum[t] = part[t] - own;  // exclusive block offset
}
// phase 3: local scan + block offset -> row_ptr, cursor
__global__ __launch_bounds__(256) void k_scan3(const int* __restrict__ deg,
                                               const int* __restrict__ bsum,
                                               int* __restrict__ row_ptr,
                                               int* __restrict__ cursor, int N) {
  __shared__ int part[256];
  const int t = threadIdx.x;
  int i = blockIdx.x * 256 + t;
  int v = (i < N) ? deg[i] : 0;
  part[t] = v;
  __syncthreads();
  for (int off = 1; off < 256; off <<= 1) {
    int x = (t >= off) ? part[t - off] : 0;
    __syncthreads();
    part[t] += x;
    __syncthreads();
  }
  int excl = part[t] - v + bsum[blockIdx.x];
  if (i < N) {
    row_ptr[i] = excl;
    cursor[i]  = excl;
    if (i == N - 1) row_ptr[N] = excl + v;
  }
}

// ---- K0f: fill CSR edge lists ------------------------------------------------
__global__ __launch_bounds__(256) void k_fill(const int* __restrict__ dst,
                                              int* __restrict__ cursor,
                                              int* __restrict__ eidx, int E) {
  int e = blockIdx.x * 256 + threadIdx.x;
  if (e >= E) return;
  int pos = atomicAdd(cursor + dst[e], 1);
  eidx[pos] = e;
}

// ---- K1: H_proj = H @ W.T (W pre-transposed to Wt[k][out], coalesced) --------
__global__ __launch_bounds__(256) void k_proj(const void* __restrict__ Hraw,
                                              const float* __restrict__ Wtf,
                                              const int* __restrict__ dflag,
                                              float* __restrict__ Hproj, int N) {
  __shared__ float Ht[32][260];
  const int t = threadIdx.x;
  const int nb = blockIdx.x * 32;
  const int dt = *dflag;
  if (dt) {  // fp32 input
    const float4* __restrict__ H4 = (const float4*)Hraw;
#pragma unroll
    for (int i = 0; i < 8; ++i) {
      int f = t + i * 256;
      int r = f >> 6, kq = f & 63;
      float4 v = make_float4(0.f, 0.f, 0.f, 0.f);
      if (nb + r < N) v = H4[(size_t)(nb + r) * 64 + kq];
      *(float4*)&Ht[r][4 * kq] = v;
    }
  } else {   // bf16 input
    const uint4* __restrict__ H8 = (const uint4*)Hraw;
#pragma unroll
    for (int i = 0; i < 4; ++i) {
      int g = t + i * 256;
      int r = g >> 5, c8 = g & 31;
      uint4 v = make_uint4(0u, 0u, 0u, 0u);
      if (nb + r < N) v = H8[(size_t)(nb + r) * 32 + c8];
      float2 f0 = bfp2(v.x), f1 = bfp2(v.y), f2 = bfp2(v.z), f3 = bfp2(v.w);
      *(float4*)&Ht[r][c8 * 8 + 0] = make_float4(f0.x, f0.y, f1.x, f1.y);
      *(float4*)&Ht[r][c8 * 8 + 4] = make_float4(f2.x, f2.y, f3.x, f3.y);
    }
  }
  __syncthreads();
  const int cg = (t & 31);          // col-group: cols 4*cg .. 4*cg+3
  const int n0 = (t >> 5) * 4;
  float acc[4][4];
#pragma unroll
  for (int n = 0; n < 4; ++n)
#pragma unroll
    for (int j = 0; j < 4; ++j) acc[n][j] = 0.f;
  const float4* __restrict__ Wt4 = (const float4*)Wtf;  // [256][32] float4
#pragma unroll 4
  for (int kk = 0; kk < 256; kk += 4) {
    float4 w0 = Wt4[(size_t)(kk + 0) * 32 + cg];
    float4 w1 = Wt4[(size_t)(kk + 1) * 32 + cg];
    float4 w2 = Wt4[(size_t)(kk + 2) * 32 + cg];
    float4 w3 = Wt4[(size_t)(kk + 3) * 32 + cg];
#pragma unroll
    for (int n = 0; n < 4; ++n) {
      float4 h = *(const float4*)&Ht[n0 + n][kk];
      acc[n][0] += h.x * w0.x + h.y * w1.x + h.z * w2.x + h.w * w3.x;
      acc[n][1] += h.x * w0.y + h.y * w1.y + h.z * w2.y + h.w * w3.y;
      acc[n][2] += h.x * w0.z + h.y * w1.z + h.z * w2.z + h.w * w3.z;
      acc[n][3] += h.x * w0.w + h.y * w1.w + h.z * w2.w + h.w * w3.w;
    }
  }
#pragma unroll
  for (int n = 0; n < 4; ++n) {
    int row = nb + n0 + n;
    if (row < N)
      *(float4*)&Hproj[(size_t)row * 128 + 4 * cg] =
          make_float4(acc[n][0], acc[n][1], acc[n][2], acc[n][3]);
  }
}

// ---- K2: per-node attention dots + msg base ----------------------------------
__global__ __launch_bounds__(256) void k_node(const float* __restrict__ Hproj,
                                              const float* __restrict__ af,   // [a_src(128)|a_dst(128)]
                                              const float* __restrict__ msgwf,
                                              float* __restrict__ s_src,
                                              float* __restrict__ s_dst,
                                              float* __restrict__ msgb, int N) {
  const int l = threadIdx.x & 63;
  const int wb = threadIdx.x >> 6;
  const int n = (blockIdx.x << 2) + wb;
  if (n >= N) return;
  const float* row = Hproj + (size_t)n * 128;
  float h0 = row[l], h1 = row[64 + l];
  float p0 = h0 * af[l],       p1 = h1 * af[64 + l];
  float q0 = h0 * af[128 + l], q1 = h1 * af[192 + l];
#pragma unroll
  for (int off = 16; off; off >>= 1) {
    p0 += __shfl_xor(p0, off);
    p1 += __shfl_xor(p1, off);
    q0 += __shfl_xor(q0, off);
    q1 += __shfl_xor(q1, off);
  }
  if (l == 0)  { s_src[n*4+0] = p0; s_src[n*4+2] = p1; s_dst[n*4+0] = q0; s_dst[n*4+2] = q1; }
  if (l == 32) { s_src[n*4+1] = p0; s_src[n*4+3] = p1; s_dst[n*4+1] = q0; s_dst[n*4+3] = q1; }
  float t4 = h0 + __shfl_xor(h0, 32) + h1 + __shfl_xor(h1, 32);
  float hbar = 0.25f * t4;  // lanes 0..31: mean over heads at d=l
  if (l < DK) {
    float acc = 0.f;
#pragma unroll
    for (int d = 0; d < DK; ++d) acc += __shfl(hbar, d) * msgwf[l * DK + d];
    msgb[(size_t)n * DK + l] = acc;
  }
}

// ---- K3: per-edge logits + LeakyReLU + per-head global max -------------------
__global__ __launch_bounds__(256) void k_logits(const int* __restrict__ src,
                                                const int* __restrict__ dst,
                                                const void* __restrict__ sim1,
                                                const int* __restrict__ dflag,
                                                const float* __restrict__ s_src,
                                                const float* __restrict__ s_dst,
                                                float4* __restrict__ e_vals,
                                                unsigned* __restrict__ gmax, int E) {
  const int e = blockIdx.x * 256 + threadIdx.x;
  float m0 = -FLT_MAX, m1 = -FLT_MAX, m2 = -FLT_MAX, m3 = -FLT_MAX;
  if (e < E) {
    int s = src[e], d = dst[e];
    float4 ss = *(const float4*)(s_src + (size_t)s * 4);
    float4 sd = *(const float4*)(s_dst + (size_t)d * 4);
    float sv = (*dflag) ? ((const float*)sim1)[e] : bf2f(((const unsigned short*)sim1)[e]);
    float b = kBeta * sv;
    float e0 = ss.x + sd.x + b; e0 = (e0 >= 0.f) ? e0 : kNeg * e0;
    float e1 = ss.y + sd.y + b; e1 = (e1 >= 0.f) ? e1 : kNeg * e1;
    float e2 = ss.z + sd.z + b; e2 = (e2 >= 0.f) ? e2 : kNeg * e2;
    float e3 = ss.w + sd.w + b; e3 = (e3 >= 0.f) ? e3 : kNeg * e3;
    e_vals[e] = make_float4(e0, e1, e2, e3);
    m0 = e0; m1 = e1; m2 = e2; m3 = e3;
  }
#pragma unroll
  for (int off = 32; off; off >>= 1) {
    m0 = fmaxf(m0, __shfl_xor(m0, off));
    m1 = fmaxf(m1, __shfl_xor(m1, off));
    m2 = fmaxf(m2, __shfl_xor(m2, off));
    m3 = fmaxf(m3, __shfl_xor(m3, off));
  }
  __shared__ float red[4][4];
  if ((threadIdx.x & 63) == 0) {
    int w = threadIdx.x >> 6;
    red[w][0] = m0; red[w][1] = m1; red[w][2] = m2; red[w][3] = m3;
  }
  __syncthreads();
  if (threadIdx.x < 4) {
    int h = threadIdx.x;
    float mm = fmaxf(fmaxf(red[0][h], red[1][h]), fmaxf(red[2][h], red[3][h]));
    atomicMax(gmax + h, fkey(mm));
  }
}

// ---- K4: msg_base gather (coalesced writes) ----------------------------------
__global__ __launch_bounds__(256) void k_msg(const int* __restrict__ src,
                                             const float* __restrict__ msgb,
                                             const int* __restrict__ dflag,
                                             void* __restrict__ d_out,
                                             int N, int E) {
  long long tid = (long long)blockIdx.x * 256 + threadIdx.x;
  if (tid >= (long long)E * DK) return;
  int e = (int)(tid >> 5), j = (int)(tid & 31);
  float mv = msgb[(size_t)src[e] * DK + j];
  const size_t msg_off = (size_t)N * 128 + (size_t)E;
  if (*dflag) ((float*)d_out)[msg_off + (size_t)e * DK + j] = mv;
  else        ((__hip_bfloat16*)d_out)[msg_off + (size_t)e * DK + j] = __float2bfloat16(mv);
}

// ---- K5: wave-per-node CSR gather: exp, denom, alpha_mean, out_h -------------
__global__ __launch_bounds__(256) void k_out(const int* __restrict__ row_ptr,
                                             const int* __restrict__ eidx,
                                             const int* __restrict__ src,
                                             const float4* __restrict__ e_vals,
                                             const unsigned* __restrict__ gmax,
                                             const float* __restrict__ Hproj,
                                             const int* __restrict__ dflag,
                                             void* __restrict__ d_out, int N, int E) {
  const int n = (int)((blockIdx.x * 256 + threadIdx.x) >> 6);
  const int l = threadIdx.x & 63;
  if (n >= N) return;
  const int beg = row_ptr[n];
  const int deg = row_ptr[n + 1] - beg;
  const int dt = *dflag;
  const float m0 = funkey(gmax[0]), m1 = funkey(gmax[1]);
  const float m2 = funkey(gmax[2]), m3 = funkey(gmax[3]);
  const size_t alpha_off = (size_t)N * 128;
  float acc_lo = 0.f, acc_hi = 0.f;
  float4 dn = make_float4(0.f, 0.f, 0.f, 0.f);
  int eid = 0, s = 0;
  float4 ev = make_float4(0.f, 0.f, 0.f, 0.f);
  const bool small = (deg <= 64);
  if (small) {
    if (l < deg) {
      eid = eidx[beg + l];
      float4 r = e_vals[eid];
      ev = make_float4(expf(r.x - m0), expf(r.y - m1),
                       expf(r.z - m2), expf(r.w - m3));
      s = src[eid];
      dn = ev;
    }
  } else {
    for (int base = 0; base < deg; base += 64) {
      if (base + l < deg) {
        int e2 = eidx[beg + base + l];
        float4 r = e_vals[e2];
        dn.x += expf(r.x - m0); dn.y += expf(r.y - m1);
        dn.z += expf(r.z - m2); dn.w += expf(r.w - m3);
      }
    }
  }
#pragma unroll
  for (int off = 32; off; off >>= 1) {
    dn.x += __shfl_xor(dn.x, off);
    dn.y += __shfl_xor(dn.y, off);
    dn.z += __shfl_xor(dn.z, off);
    dn.w += __shfl_xor(dn.w, off);
  }
  const float i0 = 1.f / (dn.x + kEps), i1 = 1.f / (dn.y + kEps);
  const float i2 = 1.f / (dn.z + kEps), i3 = 1.f / (dn.w + kEps);
  if (small) {
    if (l < deg) {
      float am = 0.25f * (ev.x * i0 + ev.y * i1 + ev.z * i2 + ev.w * i3);
      if (dt) ((float*)d_out)[alpha_off + eid] = am;
      else    ((__hip_bfloat16*)d_out)[alpha_off + eid] = __float2bfloat16(am);
    }
    for (int i = 0; i < deg; ++i) {
      int si = __shfl(s, i);
      float ax = __shfl(ev.x, i), ay = __shfl(ev.y, i);
      float az = __shfl(ev.z, i), aw = __shfl(ev.w, i);
      float a_lo = (l < 32) ? ax * i0 : ay * i1;
      float a_hi = (l < 32) ? az * i2 : aw * i3;
      acc_lo += a_lo * Hproj[(size_t)si * 128 + l];
      acc_hi += a_hi * Hproj[(size_t)si * 128 + 64 + l];
    }
  } else {
    for (int base = 0; base < deg; base += 64) {
      int cnt = min(64, deg - base);
      int eid2 = 0, s2 = 0;
      float4 e2 = make_float4(0.f, 0.f, 0.f, 0.f);
      if (l < cnt) {
        eid2 = eidx[beg + base + l];
        float4 r = e_vals[eid2];
        e2 = make_float4(expf(r.x - m0), expf(r.y - m1),
                         expf(r.z - m2), expf(r.w - m3));
        s2 = src[eid2];
        float am = 0.25f * (e2.x * i0 + e2.y * i1 + e2.z * i2 + e2.w * i3);
        if (dt) ((float*)d_out)[alpha_off + eid2] = am;
        else    ((__hip_bfloat16*)d_out)[alpha_off + eid2] = __float2bfloat16(am);
      }
      for (int i = 0; i < cnt; ++i) {
        int si = __shfl(s2, i);
        float ax = __shfl(e2.x, i), ay = __shfl(e2.y, i);
        float az = __shfl(e2.z, i), aw = __shfl(e2.w, i);
        float a_lo = (l < 32) ? ax * i0 : ay * i1;
        float a_hi = (l < 32) ? az * i2 : aw * i3;
        acc_lo += a_lo * Hproj[(size_t)si * 128 + l];
        acc_hi += a_hi * Hproj[(size_t)si * 128 + 64 + l];
      }
    }
  }
  if (dt) {
    ((float*)d_out)[(size_t)n * 128 + l]      = acc_lo;
    ((float*)d_out)[(size_t)n * 128 + 64 + l] = acc_hi;
  } else {
    ((__hip_bfloat16*)d_out)[(size_t)n * 128 + l]      = __float2bfloat16(acc_lo);
    ((__hip_bfloat16*)d_out)[(size_t)n * 128 + 64 + l] = __float2bfloat16(acc_hi);
  }
}

extern "C" void kernel_launch(void* const* d_in, const int* in_sizes, int n_in,
                              void* d_out, int out_size, void* d_ws, size_t ws_size,
                              hipStream_t stream) {
  const void* H     = d_in[0];
  const int*  ei    = (const int*)d_in[1];
  const void* sim1  = d_in[2];
  const void* W     = d_in[3];
  const void* a_src = d_in[4];
  const void* a_dst = d_in[5];
  const void* msg_w = d_in[6];
  const int N = in_sizes[0] / 256;
  const int E = in_sizes[2];
  const int NB = (N + 255) / 256;  // scan blocks (<=1024 supported)

  float* ws      = (float*)d_ws;
  float* Hproj   = ws;                           // N*128
  float* s_src   = Hproj  + (size_t)N * 128;     // N*4
  float* s_dst   = s_src  + (size_t)N * 4;       // N*4
  float* msgb    = s_dst  + (size_t)N * 4;       // N*32
  float* e_vals  = msgb   + (size_t)N * 32;      // E*4
  int* deg       = (int*)(e_vals + (size_t)E * 4);  // N   <- zeroed from here
  unsigned* gmax = (unsigned*)(deg + N);         // 4
  int* eflag     = (int*)(gmax + 4);             // 1
  int* dflag     = eflag + 1;                    // 1   <- zeroed to here
  int* row_ptr   = dflag + 1;                    // N+1
  int* cursor    = row_ptr + N + 1;              // N
  int* bsum      = cursor + N;                   // 1024
  int* eidx      = bsum + 1024;                  // E
  int* src_i     = eidx + E;                     // E
  int* dst_i     = src_i + E;                    // E
  float* Wtf     = (float*)(dst_i + E);          // 256*128 (transposed W)
  float* af      = Wtf + 128 * 256;              // 256: [a_src|a_dst]
  float* msgwf   = af + 256;                     // 1024

  hipMemsetAsync(deg, 0, (size_t)(N + 6) * sizeof(int), stream);

  k_detect_edges<<<16, 256, 0, stream>>>(ei, eflag, E);
  k_detect_dtype<<<512, 256, 0, stream>>>((const unsigned*)H, dflag, 131072);
  k_cvt<<<(E + 255) / 256, 256, 0, stream>>>(ei, eflag, src_i, dst_i, deg, E);
  k_wcvt<<<128, 256, 0, stream>>>(W, Wtf, dflag, 128 * 256);
  k_f32cvt<<<1, 256, 0, stream>>>(a_src, af, dflag, 128);
  k_f32cvt<<<1, 256, 0, stream>>>(a_dst, af + 128, dflag, 128);
  k_f32cvt<<<4, 256, 0, stream>>>(msg_w, msgwf, dflag, 1024);
  k_proj<<<(N + 31) / 32, 256, 0, stream>>>(H, Wtf, dflag, Hproj, N);
  k_scan1<<<NB, 256, 0, stream>>>(deg, bsum, N);
  k_scan2<<<1, 1024, 0, stream>>>(bsum, NB);
  k_scan3<<<NB, 256, 0, stream>>>(deg, bsum, row_ptr, cursor, N);
  k_fill<<<(E + 255) / 256, 256, 0, stream>>>(dst_i, cursor, eidx, E);
  k_node<<<(N + 3) / 4, 256, 0, stream>>>(Hproj, af, msgwf, s_src, s_dst, msgb, N);
  k_logits<<<(E + 255) / 256, 256, 0, stream>>>(src_i, dst_i, sim1, dflag, s_src, s_dst,
                                                (float4*)e_vals, gmax, E);
  k_msg<<<(int)(((long long)E * DK + 255) / 256), 256, 0, stream>>>(src_i, msgb, dflag,
                                                                    d_out, N, E);
  k_out<<<(int)(((size_t)N * 64 + 255) / 256), 256, 0, stream>>>(
      row_ptr, eidx, src_i, (const float4*)e_vals, gmax, Hproj, dflag, d_out, N, E);
}

// Round 4
// 515.113 us; speedup vs baseline: 1.9302x; 1.0564x over previous
//
#include <hip/hip_runtime.h>
#include <hip/hip_bf16.h>
#include <hip/hip_fp16.h>
#include <float.h>

#define HEADS 4
#define DK 32

static constexpr float kBeta = 1.0f;
static constexpr float kNeg  = 0.2f;
static constexpr float kEps  = 1e-12f;

__device__ __forceinline__ float bf2f(unsigned short v) {
  return __uint_as_float((unsigned)v << 16);
}
__device__ __forceinline__ float2 bfp2(unsigned u) {
  return make_float2(__uint_as_float(u << 16), __uint_as_float(u & 0xFFFF0000u));
}
// order-preserving float <-> uint key for atomicMax
__device__ __forceinline__ unsigned fkey(float x) {
  unsigned u = __float_as_uint(x);
  return (u & 0x80000000u) ? ~u : (u | 0x80000000u);
}
__device__ __forceinline__ float funkey(unsigned k) {
  unsigned u = (k & 0x80000000u) ? (k & 0x7fffffffu) : ~k;
  return __uint_as_float(u);
}

// ---- K0a: fused detect: edge layout (int64 -> odd words 0) + float dtype -----
__global__ __launch_bounds__(256) void k_detect(const int* __restrict__ ei32,
                                                const unsigned* __restrict__ Hw,
                                                int* __restrict__ eflag,
                                                int* __restrict__ dflag,
                                                int E, int nw) {
  int i = blockIdx.x * 256 + threadIdx.x;
  if (i < 4096 && 2 * i + 1 < 2 * E && ei32[2 * i + 1] != 0) atomicOr(eflag, 1);
  if (i < nw && ((Hw[i] >> 7) & 0xFFu) == 0xFFu) atomicOr(dflag, 1);
}

// ---- K0c: normalize edge index into int32 src/dst + degree histogram ---------
__global__ __launch_bounds__(256) void k_cvt(const int* __restrict__ ei32,
                                             const int* __restrict__ eflag,
                                             int* __restrict__ src_i,
                                             int* __restrict__ dst_i,
                                             int* __restrict__ deg, int E) {
  int i = blockIdx.x * 256 + threadIdx.x;
  if (i >= E) return;
  int s, d;
  if (*eflag) { s = ei32[i];     d = ei32[E + i]; }
  else        { s = ei32[2 * i]; d = ei32[2 * E + 2 * i]; }
  src_i[i] = s;
  dst_i[i] = d;
  atomicAdd(deg + d, 1);
}

// ---- K0d: small params convert (a_src | a_dst | msg_lin_w) -------------------
__global__ __launch_bounds__(256) void k_params(const void* __restrict__ a_src,
                                                const void* __restrict__ a_dst,
                                                const void* __restrict__ msg_w,
                                                float* __restrict__ af,
                                                float* __restrict__ msgwf,
                                                const int* __restrict__ dflag) {
  int i = blockIdx.x * 256 + threadIdx.x;  // [0, 1280)
  int dt = *dflag;
  if (i < 128) {
    af[i] = dt ? ((const float*)a_src)[i] : bf2f(((const unsigned short*)a_src)[i]);
  } else if (i < 256) {
    int j = i - 128;
    af[i] = dt ? ((const float*)a_dst)[j] : bf2f(((const unsigned short*)a_dst)[j]);
  } else if (i < 1280) {
    int j = i - 256;
    msgwf[j] = dt ? ((const float*)msg_w)[j] : bf2f(((const unsigned short*)msg_w)[j]);
  }
}

// ---- K0d': W convert + transpose: Wt[k][out] = W[out][k] ---------------------
__global__ __launch_bounds__(256) void k_wcvt(const void* __restrict__ in,
                                              float* __restrict__ out,
                                              const int* __restrict__ dflag, int n) {
  int i = blockIdx.x * 256 + threadIdx.x;  // i = r*256 + c, r: out-row, c: k
  if (i >= n) return;
  int r = i >> 8, c = i & 255;
  float v = (*dflag) ? ((const float*)in)[i] : bf2f(((const unsigned short*)in)[i]);
  out[(size_t)c * 128 + r] = v;
}

// ---- K0e: 3-phase device-wide exclusive scan of deg --------------------------
__global__ __launch_bounds__(256) void k_scan1(const int* __restrict__ deg,
                                               int* __restrict__ bsum, int N) {
  const int t = threadIdx.x;
  int i = blockIdx.x * 256 + t;
  int v = (i < N) ? deg[i] : 0;
#pragma unroll
  for (int off = 32; off; off >>= 1) v += __shfl_xor(v, off);
  __shared__ int red[4];
  if ((t & 63) == 0) red[t >> 6] = v;
  __syncthreads();
  if (t == 0) bsum[blockIdx.x] = red[0] + red[1] + red[2] + red[3];
}
__global__ __launch_bounds__(1024) void k_scan2(int* __restrict__ bsum, int nb) {
  __shared__ int part[1024];
  const int t = threadIdx.x;
  part[t] = (t < nb) ? bsum[t] : 0;
  __syncthreads();
  int own = part[t];
  for (int off = 1; off < 1024; off <<= 1) {
    int v = (t >= off) ? part[t - off] : 0;
    __syncthreads();
    part[t] += v;
    __syncthreads();
  }
  if (t < nb) bsum[t] = part[t] - own;  // exclusive block offset
}
__global__ __launch_bounds__(256) void k_scan3(const int* __restrict__ deg,
                                               const int* __restrict__ bsum,
                                               int* __restrict__ row_ptr,
                                               int* __restrict__ cursor, int N) {
  __shared__ int part[256];
  const int t = threadIdx.x;
  int i = blockIdx.x * 256 + t;
  int v = (i < N) ? deg[i] : 0;
  part[t] = v;
  __syncthreads();
  for (int off = 1; off < 256; off <<= 1) {
    int x = (t >= off) ? part[t - off] : 0;
    __syncthreads();
    part[t] += x;
    __syncthreads();
  }
  int excl = part[t] - v + bsum[blockIdx.x];
  if (i < N) {
    row_ptr[i] = excl;
    cursor[i]  = excl;
    if (i == N - 1) row_ptr[N] = excl + v;
  }
}

// ---- K0f: fill CSR edge lists ------------------------------------------------
__global__ __launch_bounds__(256) void k_fill(const int* __restrict__ dst,
                                              int* __restrict__ cursor,
                                              int* __restrict__ eidx, int E) {
  int e = blockIdx.x * 256 + threadIdx.x;
  if (e >= E) return;
  int pos = atomicAdd(cursor + dst[e], 1);
  eidx[pos] = e;
}

// ---- K1: H_proj = H @ W.T (W pre-transposed to Wt[k][out], coalesced) --------
__global__ __launch_bounds__(256) void k_proj(const void* __restrict__ Hraw,
                                              const float* __restrict__ Wtf,
                                              const int* __restrict__ dflag,
                                              float* __restrict__ Hproj, int N) {
  __shared__ float Ht[32][260];
  const int t = threadIdx.x;
  const int nb = blockIdx.x * 32;
  const int dt = *dflag;
  if (dt) {  // fp32 input
    const float4* __restrict__ H4 = (const float4*)Hraw;
#pragma unroll
    for (int i = 0; i < 8; ++i) {
      int f = t + i * 256;
      int r = f >> 6, kq = f & 63;
      float4 v = make_float4(0.f, 0.f, 0.f, 0.f);
      if (nb + r < N) v = H4[(size_t)(nb + r) * 64 + kq];
      *(float4*)&Ht[r][4 * kq] = v;
    }
  } else {   // bf16 input
    const uint4* __restrict__ H8 = (const uint4*)Hraw;
#pragma unroll
    for (int i = 0; i < 4; ++i) {
      int g = t + i * 256;
      int r = g >> 5, c8 = g & 31;
      uint4 v = make_uint4(0u, 0u, 0u, 0u);
      if (nb + r < N) v = H8[(size_t)(nb + r) * 32 + c8];
      float2 f0 = bfp2(v.x), f1 = bfp2(v.y), f2 = bfp2(v.z), f3 = bfp2(v.w);
      *(float4*)&Ht[r][c8 * 8 + 0] = make_float4(f0.x, f0.y, f1.x, f1.y);
      *(float4*)&Ht[r][c8 * 8 + 4] = make_float4(f2.x, f2.y, f3.x, f3.y);
    }
  }
  __syncthreads();
  const int cg = (t & 31);          // col-group: cols 4*cg .. 4*cg+3
  const int n0 = (t >> 5) * 4;
  float acc[4][4];
#pragma unroll
  for (int n = 0; n < 4; ++n)
#pragma unroll
    for (int j = 0; j < 4; ++j) acc[n][j] = 0.f;
  const float4* __restrict__ Wt4 = (const float4*)Wtf;  // [256][32] float4
#pragma unroll 4
  for (int kk = 0; kk < 256; kk += 4) {
    float4 w0 = Wt4[(size_t)(kk + 0) * 32 + cg];
    float4 w1 = Wt4[(size_t)(kk + 1) * 32 + cg];
    float4 w2 = Wt4[(size_t)(kk + 2) * 32 + cg];
    float4 w3 = Wt4[(size_t)(kk + 3) * 32 + cg];
#pragma unroll
    for (int n = 0; n < 4; ++n) {
      float4 h = *(const float4*)&Ht[n0 + n][kk];
      acc[n][0] += h.x * w0.x + h.y * w1.x + h.z * w2.x + h.w * w3.x;
      acc[n][1] += h.x * w0.y + h.y * w1.y + h.z * w2.y + h.w * w3.y;
      acc[n][2] += h.x * w0.z + h.y * w1.z + h.z * w2.z + h.w * w3.z;
      acc[n][3] += h.x * w0.w + h.y * w1.w + h.z * w2.w + h.w * w3.w;
    }
  }
#pragma unroll
  for (int n = 0; n < 4; ++n) {
    int row = nb + n0 + n;
    if (row < N)
      *(float4*)&Hproj[(size_t)row * 128 + 4 * cg] =
          make_float4(acc[n][0], acc[n][1], acc[n][2], acc[n][3]);
  }
}

// ---- K2: per-node attention dots + msg base + fp16 copies --------------------
__global__ __launch_bounds__(256) void k_node(const float* __restrict__ Hproj,
                                              const float* __restrict__ af,   // [a_src(128)|a_dst(128)]
                                              const float* __restrict__ msgwf,
                                              float* __restrict__ s_src,
                                              float* __restrict__ s_dst,
                                              __half* __restrict__ msgb,
                                              __half* __restrict__ Hb, int N) {
  const int l = threadIdx.x & 63;
  const int wb = threadIdx.x >> 6;
  const int n = (blockIdx.x << 2) + wb;
  if (n >= N) return;
  const float* row = Hproj + (size_t)n * 128;
  float h0 = row[l], h1 = row[64 + l];
  // fp16 copy for the k_out gather (half the bytes; err <= ~0.002)
  Hb[(size_t)n * 128 + l]      = __float2half(h0);
  Hb[(size_t)n * 128 + 64 + l] = __float2half(h1);
  float p0 = h0 * af[l],       p1 = h1 * af[64 + l];
  float q0 = h0 * af[128 + l], q1 = h1 * af[192 + l];
#pragma unroll
  for (int off = 16; off; off >>= 1) {
    p0 += __shfl_xor(p0, off);
    p1 += __shfl_xor(p1, off);
    q0 += __shfl_xor(q0, off);
    q1 += __shfl_xor(q1, off);
  }
  if (l == 0)  { s_src[n*4+0] = p0; s_src[n*4+2] = p1; s_dst[n*4+0] = q0; s_dst[n*4+2] = q1; }
  if (l == 32) { s_src[n*4+1] = p0; s_src[n*4+3] = p1; s_dst[n*4+1] = q0; s_dst[n*4+3] = q1; }
  float t4 = h0 + __shfl_xor(h0, 32) + h1 + __shfl_xor(h1, 32);
  float hbar = 0.25f * t4;  // lanes 0..31: mean over heads at d=l
  if (l < DK) {
    float acc = 0.f;
#pragma unroll
    for (int d = 0; d < DK; ++d) acc += __shfl(hbar, d) * msgwf[l * DK + d];
    msgb[(size_t)n * DK + l] = __float2half(acc);
  }
}

// ---- K3: per-edge logits + LeakyReLU + per-head global max (no e_vals store) -
__global__ __launch_bounds__(256) void k_logits(const int* __restrict__ src,
                                                const int* __restrict__ dst,
                                                const void* __restrict__ sim1,
                                                const int* __restrict__ dflag,
                                                const float* __restrict__ s_src,
                                                const float* __restrict__ s_dst,
                                                unsigned* __restrict__ gmax, int E) {
  const int e = blockIdx.x * 256 + threadIdx.x;
  float m0 = -FLT_MAX, m1 = -FLT_MAX, m2 = -FLT_MAX, m3 = -FLT_MAX;
  if (e < E) {
    int s = src[e], d = dst[e];
    float4 ss = *(const float4*)(s_src + (size_t)s * 4);
    float4 sd = *(const float4*)(s_dst + (size_t)d * 4);
    float sv = (*dflag) ? ((const float*)sim1)[e] : bf2f(((const unsigned short*)sim1)[e]);
    float b = kBeta * sv;
    float e0 = ss.x + sd.x + b; e0 = (e0 >= 0.f) ? e0 : kNeg * e0;
    float e1 = ss.y + sd.y + b; e1 = (e1 >= 0.f) ? e1 : kNeg * e1;
    float e2 = ss.z + sd.z + b; e2 = (e2 >= 0.f) ? e2 : kNeg * e2;
    float e3 = ss.w + sd.w + b; e3 = (e3 >= 0.f) ? e3 : kNeg * e3;
    m0 = e0; m1 = e1; m2 = e2; m3 = e3;
  }
#pragma unroll
  for (int off = 32; off; off >>= 1) {
    m0 = fmaxf(m0, __shfl_xor(m0, off));
    m1 = fmaxf(m1, __shfl_xor(m1, off));
    m2 = fmaxf(m2, __shfl_xor(m2, off));
    m3 = fmaxf(m3, __shfl_xor(m3, off));
  }
  __shared__ float red[4][4];
  if ((threadIdx.x & 63) == 0) {
    int w = threadIdx.x >> 6;
    red[w][0] = m0; red[w][1] = m1; red[w][2] = m2; red[w][3] = m3;
  }
  __syncthreads();
  if (threadIdx.x < 4) {
    int h = threadIdx.x;
    float mm = fmaxf(fmaxf(red[0][h], red[1][h]), fmaxf(red[2][h], red[3][h]));
    atomicMax(gmax + h, fkey(mm));
  }
}

// ---- K4: msg_base gather (fp16 table, L2-resident; float2 coalesced writes) --
__global__ __launch_bounds__(256) void k_msg(const int* __restrict__ src,
                                             const __half2* __restrict__ msgb2,
                                             const int* __restrict__ dflag,
                                             void* __restrict__ d_out,
                                             int N, int E) {
  long long tid = (long long)blockIdx.x * 256 + threadIdx.x;
  if (tid >= (long long)E * 16) return;
  int e = (int)(tid >> 4), jp = (int)(tid & 15);
  __half2 hv = msgb2[(size_t)src[e] * 16 + jp];
  float2 f = __half22float2(hv);
  const size_t msg_off = (size_t)N * 128 + (size_t)E;
  if (*dflag) {
    *(float2*)&((float*)d_out)[msg_off + (size_t)e * 32 + 2 * jp] = f;
  } else {
    __hip_bfloat162 b = __float22bfloat162_rn(f);
    *(__hip_bfloat162*)((__hip_bfloat16*)d_out + msg_off + (size_t)e * 32 + 2 * jp) = b;
  }
}

// ---- K5: wave-per-node CSR gather: recomputed logits, fp16 Hb gather ---------
__global__ __launch_bounds__(256) void k_out(const int* __restrict__ row_ptr,
                                             const int* __restrict__ eidx,
                                             const int* __restrict__ src,
                                             const void* __restrict__ sim1,
                                             const float* __restrict__ s_src,
                                             const float* __restrict__ s_dst,
                                             const unsigned* __restrict__ gmax,
                                             const unsigned* __restrict__ Hb_u,
                                             const int* __restrict__ dflag,
                                             void* __restrict__ d_out, int N, int E) {
  const int n = (int)((blockIdx.x * 256 + threadIdx.x) >> 6);
  const int l = threadIdx.x & 63;
  if (n >= N) return;
  const int beg = row_ptr[n];
  const int deg = row_ptr[n + 1] - beg;
  const int dt = *dflag;
  const float m0 = funkey(gmax[0]), m1 = funkey(gmax[1]);
  const float m2 = funkey(gmax[2]), m3 = funkey(gmax[3]);
  const float4 sd = *(const float4*)(s_dst + (size_t)n * 4);  // wave-uniform
  const size_t alpha_off = (size_t)N * 128;
  float accx = 0.f, accy = 0.f;
  float4 dn = make_float4(0.f, 0.f, 0.f, 0.f);
  int eid = 0, s = 0;
  float4 ev = make_float4(0.f, 0.f, 0.f, 0.f);
  const bool small = (deg <= 64);
  if (small) {
    if (l < deg) {
      eid = eidx[beg + l];
      s = src[eid];
      float4 ss = *(const float4*)(s_src + (size_t)s * 4);
      float sv = dt ? ((const float*)sim1)[eid] : bf2f(((const unsigned short*)sim1)[eid]);
      float e0 = ss.x + sd.x + sv; e0 = (e0 >= 0.f) ? e0 : kNeg * e0;
      float e1 = ss.y + sd.y + sv; e1 = (e1 >= 0.f) ? e1 : kNeg * e1;
      float e2 = ss.z + sd.z + sv; e2 = (e2 >= 0.f) ? e2 : kNeg * e2;
      float e3 = ss.w + sd.w + sv; e3 = (e3 >= 0.f) ? e3 : kNeg * e3;
      ev = make_float4(expf(e0 - m0), expf(e1 - m1), expf(e2 - m2), expf(e3 - m3));
      dn = ev;
    }
  } else {
    for (int base = 0; base < deg; base += 64) {
      if (base + l < deg) {
        int e2i = eidx[beg + base + l];
        int s2 = src[e2i];
        float4 ss = *(const float4*)(s_src + (size_t)s2 * 4);
        float sv = dt ? ((const float*)sim1)[e2i] : bf2f(((const unsigned short*)sim1)[e2i]);
        float e0 = ss.x + sd.x + sv; e0 = (e0 >= 0.f) ? e0 : kNeg * e0;
        float e1 = ss.y + sd.y + sv; e1 = (e1 >= 0.f) ? e1 : kNeg * e1;
        float e2 = ss.z + sd.z + sv; e2 = (e2 >= 0.f) ? e2 : kNeg * e2;
        float e3 = ss.w + sd.w + sv; e3 = (e3 >= 0.f) ? e3 : kNeg * e3;
        dn.x += expf(e0 - m0); dn.y += expf(e1 - m1);
        dn.z += expf(e2 - m2); dn.w += expf(e3 - m3);
      }
    }
  }
#pragma unroll
  for (int off = 32; off; off >>= 1) {
    dn.x += __shfl_xor(dn.x, off);
    dn.y += __shfl_xor(dn.y, off);
    dn.z += __shfl_xor(dn.z, off);
    dn.w += __shfl_xor(dn.w, off);
  }
  const float i0 = 1.f / (dn.x + kEps), i1 = 1.f / (dn.y + kEps);
  const float i2 = 1.f / (dn.z + kEps), i3 = 1.f / (dn.w + kEps);
  const float myinv = (l < 32) ? ((l < 16) ? i0 : i1) : ((l < 48) ? i2 : i3);
  if (small) {
    if (l < deg) {
      float am = 0.25f * (ev.x * i0 + ev.y * i1 + ev.z * i2 + ev.w * i3);
      if (dt) ((float*)d_out)[alpha_off + eid] = am;
      else    ((__hip_bfloat16*)d_out)[alpha_off + eid] = __float2bfloat16(am);
    }
    for (int i = 0; i < deg; ++i) {
      int si = __shfl(s, i);
      float ax = __shfl(ev.x, i), ay = __shfl(ev.y, i);
      float az = __shfl(ev.z, i), aw = __shfl(ev.w, i);
      float aa = ((l < 32) ? ((l < 16) ? ax : ay) : ((l < 48) ? az : aw)) * myinv;
      unsigned u = Hb_u[(size_t)si * 64 + l];
      float2 f = __half22float2(*(const __half2*)&u);
      accx += aa * f.x;
      accy += aa * f.y;
    }
  } else {
    for (int base = 0; base < deg; base += 64) {
      int cnt = min(64, deg - base);
      int eid2 = 0, s2 = 0;
      float4 e2v = make_float4(0.f, 0.f, 0.f, 0.f);
      if (l < cnt) {
        eid2 = eidx[beg + base + l];
        s2 = src[eid2];
        float4 ss = *(const float4*)(s_src + (size_t)s2 * 4);
        float sv = dt ? ((const float*)sim1)[eid2] : bf2f(((const unsigned short*)sim1)[eid2]);
        float e0 = ss.x + sd.x + sv; e0 = (e0 >= 0.f) ? e0 : kNeg * e0;
        float e1 = ss.y + sd.y + sv; e1 = (e1 >= 0.f) ? e1 : kNeg * e1;
        float e2 = ss.z + sd.z + sv; e2 = (e2 >= 0.f) ? e2 : kNeg * e2;
        float e3 = ss.w + sd.w + sv; e3 = (e3 >= 0.f) ? e3 : kNeg * e3;
        e2v = make_float4(expf(e0 - m0), expf(e1 - m1), expf(e2 - m2), expf(e3 - m3));
        float am = 0.25f * (e2v.x * i0 + e2v.y * i1 + e2v.z * i2 + e2v.w * i3);
        if (dt) ((float*)d_out)[alpha_off + eid2] = am;
        else    ((__hip_bfloat16*)d_out)[alpha_off + eid2] = __float2bfloat16(am);
      }
      for (int i = 0; i < cnt; ++i) {
        int si = __shfl(s2, i);
        float ax = __shfl(e2v.x, i), ay = __shfl(e2v.y, i);
        float az = __shfl(e2v.z, i), aw = __shfl(e2v.w, i);
        float aa = ((l < 32) ? ((l < 16) ? ax : ay) : ((l < 48) ? az : aw)) * myinv;
        unsigned u = Hb_u[(size_t)si * 64 + l];
        float2 f = __half22float2(*(const __half2*)&u);
        accx += aa * f.x;
        accy += aa * f.y;
      }
    }
  }
  if (dt) {
    *(float2*)&((float*)d_out)[(size_t)n * 128 + 2 * l] = make_float2(accx, accy);
  } else {
    __hip_bfloat162 b = __float22bfloat162_rn(make_float2(accx, accy));
    *(__hip_bfloat162*)((__hip_bfloat16*)d_out + (size_t)n * 128 + 2 * l) = b;
  }
}

extern "C" void kernel_launch(void* const* d_in, const int* in_sizes, int n_in,
                              void* d_out, int out_size, void* d_ws, size_t ws_size,
                              hipStream_t stream) {
  const void* H     = d_in[0];
  const int*  ei    = (const int*)d_in[1];
  const void* sim1  = d_in[2];
  const void* W     = d_in[3];
  const void* a_src = d_in[4];
  const void* a_dst = d_in[5];
  const void* msg_w = d_in[6];
  const int N = in_sizes[0] / 256;
  const int E = in_sizes[2];
  const int NB = (N + 255) / 256;  // scan blocks (<=1024 supported)

  char* base     = (char*)d_ws;
  float* Hproj   = (float*)base;  base += (size_t)N * 128 * 4;
  float* s_src   = (float*)base;  base += (size_t)N * 4 * 4;
  float* s_dst   = (float*)base;  base += (size_t)N * 4 * 4;
  __half* msgb   = (__half*)base; base += (size_t)N * DK * 2;
  __half* Hb     = (__half*)base; base += (size_t)N * 128 * 2;
  int* deg       = (int*)base;    base += (size_t)N * 4;   // <- zeroed from here
  unsigned* gmax = (unsigned*)base; base += 4 * 4;
  int* eflag     = (int*)base;    base += 4;
  int* dflag     = (int*)base;    base += 4;               // <- zeroed to here
  int* row_ptr   = (int*)base;    base += (size_t)(N + 1) * 4;
  int* cursor    = (int*)base;    base += (size_t)N * 4;
  int* bsum      = (int*)base;    base += 1024 * 4;
  int* eidx      = (int*)base;    base += (size_t)E * 4;
  int* src_i     = (int*)base;    base += (size_t)E * 4;
  int* dst_i     = (int*)base;    base += (size_t)E * 4;
  float* Wtf     = (float*)base;  base += 128 * 256 * 4;
  float* af      = (float*)base;  base += 256 * 4;
  float* msgwf   = (float*)base;  base += 1024 * 4;

  hipMemsetAsync(deg, 0, (size_t)(N + 6) * sizeof(int), stream);

  k_detect<<<512, 256, 0, stream>>>(ei, (const unsigned*)H, eflag, dflag, E, 131072);
  k_cvt<<<(E + 255) / 256, 256, 0, stream>>>(ei, eflag, src_i, dst_i, deg, E);
  k_wcvt<<<128, 256, 0, stream>>>(W, Wtf, dflag, 128 * 256);
  k_params<<<5, 256, 0, stream>>>(a_src, a_dst, msg_w, af, msgwf, dflag);
  k_proj<<<(N + 31) / 32, 256, 0, stream>>>(H, Wtf, dflag, Hproj, N);
  k_scan1<<<NB, 256, 0, stream>>>(deg, bsum, N);
  k_scan2<<<1, 1024, 0, stream>>>(bsum, NB);
  k_scan3<<<NB, 256, 0, stream>>>(deg, bsum, row_ptr, cursor, N);
  k_fill<<<(E + 255) / 256, 256, 0, stream>>>(dst_i, cursor, eidx, E);
  k_node<<<(N + 3) / 4, 256, 0, stream>>>(Hproj, af, msgwf, s_src, s_dst, msgb, Hb, N);
  k_logits<<<(E + 255) / 256, 256, 0, stream>>>(src_i, dst_i, sim1, dflag, s_src, s_dst,
                                                gmax, E);
  k_msg<<<(int)(((long long)E * 16 + 255) / 256), 256, 0, stream>>>(
      src_i, (const __half2*)msgb, dflag, d_out, N, E);
  k_out<<<(int)(((size_t)N * 64 + 255) / 256), 256, 0, stream>>>(
      row_ptr, eidx, src_i, sim1, s_src, s_dst, gmax, (const unsigned*)Hb, dflag,
      d_out, N, E);
}

// Round 5
// 483.811 us; speedup vs baseline: 2.0551x; 1.0647x over previous
//
#include <hip/hip_runtime.h>
#include <hip/hip_bf16.h>
#include <hip/hip_fp16.h>
#include <float.h>

#define HEADS 4
#define DK 32

static constexpr float kBeta = 1.0f;
static constexpr float kNeg  = 0.2f;
static constexpr float kEps  = 1e-12f;

typedef __bf16 bf16x8 __attribute__((ext_vector_type(8)));
typedef float  f32x4  __attribute__((ext_vector_type(4)));

__device__ __forceinline__ float bf2f(unsigned short v) {
  return __uint_as_float((unsigned)v << 16);
}
// round-to-nearest-even f32 -> bf16 bits
__device__ __forceinline__ unsigned short f2bf(float f) {
  unsigned u = __float_as_uint(f);
  unsigned r = u + 0x7FFFu + ((u >> 16) & 1u);
  return (unsigned short)(r >> 16);
}
__device__ __forceinline__ float2 bfp2(unsigned u) {
  return make_float2(__uint_as_float(u << 16), __uint_as_float(u & 0xFFFF0000u));
}
// order-preserving float <-> uint key for atomicMax
__device__ __forceinline__ unsigned fkey(float x) {
  unsigned u = __float_as_uint(x);
  return (u & 0x80000000u) ? ~u : (u | 0x80000000u);
}
__device__ __forceinline__ float funkey(unsigned k) {
  unsigned u = (k & 0x80000000u) ? (k & 0x7fffffffu) : ~k;
  return __uint_as_float(u);
}
__device__ __forceinline__ bf16x8 as8(uint4 v) {
  union { uint4 u; bf16x8 b; } x; x.u = v; return x.b;
}

// ---- K0a: fused detect: edge layout (int64 -> odd words 0) + float dtype -----
__global__ __launch_bounds__(256) void k_detect(const int* __restrict__ ei32,
                                                const unsigned* __restrict__ Hw,
                                                int* __restrict__ eflag,
                                                int* __restrict__ dflag,
                                                int E, int nw) {
  int i = blockIdx.x * 256 + threadIdx.x;
  if (i < 4096 && 2 * i + 1 < 2 * E && ei32[2 * i + 1] != 0) atomicOr(eflag, 1);
  if (i < nw && ((Hw[i] >> 7) & 0xFFu) == 0xFFu) atomicOr(dflag, 1);
}

// ---- K0c: normalize edge index into int32 src/dst + degree histogram ---------
__global__ __launch_bounds__(256) void k_cvt(const int* __restrict__ ei32,
                                             const int* __restrict__ eflag,
                                             int* __restrict__ src_i,
                                             int* __restrict__ dst_i,
                                             int* __restrict__ deg, int E) {
  int i = blockIdx.x * 256 + threadIdx.x;
  if (i >= E) return;
  int s, d;
  if (*eflag) { s = ei32[i];     d = ei32[E + i]; }
  else        { s = ei32[2 * i]; d = ei32[2 * E + 2 * i]; }
  src_i[i] = s;
  dst_i[i] = d;
  atomicAdd(deg + d, 1);
}

// ---- K0d: small params convert (a_src | a_dst | msg_lin_w) -------------------
__global__ __launch_bounds__(256) void k_params(const void* __restrict__ a_src,
                                                const void* __restrict__ a_dst,
                                                const void* __restrict__ msg_w,
                                                float* __restrict__ af,
                                                float* __restrict__ msgwf,
                                                const int* __restrict__ dflag) {
  int i = blockIdx.x * 256 + threadIdx.x;  // [0, 1280)
  int dt = *dflag;
  if (i < 128) {
    af[i] = dt ? ((const float*)a_src)[i] : bf2f(((const unsigned short*)a_src)[i]);
  } else if (i < 256) {
    int j = i - 128;
    af[i] = dt ? ((const float*)a_dst)[j] : bf2f(((const unsigned short*)a_dst)[j]);
  } else if (i < 1280) {
    int j = i - 256;
    msgwf[j] = dt ? ((const float*)msg_w)[j] : bf2f(((const unsigned short*)msg_w)[j]);
  }
}

// ---- K0d': W -> MFMA B-fragment pack (hi/lo bf16 split) ----------------------
// B[k][col] = W[col][k]; frag: lane l holds col = l&15, k = kt*32 + (l>>4)*8 + e
__global__ __launch_bounds__(256) void k_wpack(const void* __restrict__ in,
                                               unsigned short* __restrict__ Bhi,
                                               unsigned short* __restrict__ Blo,
                                               const int* __restrict__ dflag, int n) {
  int i = blockIdx.x * 256 + threadIdx.x;  // i = r*256 + c, r: out-col, c: k
  if (i >= n) return;
  int r = i >> 8, c = i & 255;
  float v = (*dflag) ? ((const float*)in)[i] : bf2f(((const unsigned short*)in)[i]);
  unsigned short hb = f2bf(v);
  unsigned short lb = f2bf(v - bf2f(hb));
  int kt = c >> 5, ct = r >> 4;
  int lane = (((c >> 3) & 3) << 4) | (r & 15);
  int idx = ((kt * 8 + ct) * 64 + lane) * 8 + (c & 7);
  Bhi[idx] = hb;
  Blo[idx] = lb;
}

// ---- K0e: 3-phase device-wide exclusive scan of deg --------------------------
__global__ __launch_bounds__(256) void k_scan1(const int* __restrict__ deg,
                                               int* __restrict__ bsum, int N) {
  const int t = threadIdx.x;
  int i = blockIdx.x * 256 + t;
  int v = (i < N) ? deg[i] : 0;
#pragma unroll
  for (int off = 32; off; off >>= 1) v += __shfl_xor(v, off);
  __shared__ int red[4];
  if ((t & 63) == 0) red[t >> 6] = v;
  __syncthreads();
  if (t == 0) bsum[blockIdx.x] = red[0] + red[1] + red[2] + red[3];
}
__global__ __launch_bounds__(1024) void k_scan2(int* __restrict__ bsum, int nb) {
  __shared__ int part[1024];
  const int t = threadIdx.x;
  part[t] = (t < nb) ? bsum[t] : 0;
  __syncthreads();
  int own = part[t];
  for (int off = 1; off < 1024; off <<= 1) {
    int v = (t >= off) ? part[t - off] : 0;
    __syncthreads();
    part[t] += v;
    __syncthreads();
  }
  if (t < nb) bsum[t] = part[t] - own;  // exclusive block offset
}
__global__ __launch_bounds__(256) void k_scan3(const int* __restrict__ deg,
                                               const int* __restrict__ bsum,
                                               int* __restrict__ row_ptr,
                                               int* __restrict__ cursor, int N) {
  __shared__ int part[256];
  const int t = threadIdx.x;
  int i = blockIdx.x * 256 + t;
  int v = (i < N) ? deg[i] : 0;
  part[t] = v;
  __syncthreads();
  for (int off = 1; off < 256; off <<= 1) {
    int x = (t >= off) ? part[t - off] : 0;
    __syncthreads();
    part[t] += x;
    __syncthreads();
  }
  int excl = part[t] - v + bsum[blockIdx.x];
  if (i < N) {
    row_ptr[i] = excl;
    cursor[i]  = excl;
    if (i == N - 1) row_ptr[N] = excl + v;
  }
}

// ---- K0f: fill CSR edge lists ------------------------------------------------
__global__ __launch_bounds__(256) void k_fill(const int* __restrict__ dst,
                                              int* __restrict__ cursor,
                                              int* __restrict__ eidx, int E) {
  int e = blockIdx.x * 256 + threadIdx.x;
  if (e >= E) return;
  int pos = atomicAdd(cursor + dst[e], 1);
  eidx[pos] = e;
}

// ---- K1: H_proj = H @ W.T via MFMA (bf16 hi/lo split; 64 rows/block) ---------
__global__ __launch_bounds__(256) void k_proj(const void* __restrict__ Hraw,
                                              const unsigned short* __restrict__ Bhi,
                                              const unsigned short* __restrict__ Blo,
                                              const int* __restrict__ dflag,
                                              float* __restrict__ Hproj, int N) {
  __shared__ uint4 lds4[4096];  // [0,2048): A_hi frags, [2048,4096): A_lo frags
  const int t = threadIdx.x;
  const int nb = blockIdx.x * 64;
  const int dt = *dflag;
  // stage A: chunk c = (row, k8); slot = (k8*64+row) ^ (k8&7)  (bank swizzle)
  if (dt) {  // fp32 input: split into hi+lo bf16
    const float4* __restrict__ H4 = (const float4*)Hraw;
#pragma unroll
    for (int it = 0; it < 8; ++it) {
      int c = it * 256 + t;
      int row = c >> 5, k8 = c & 31;
      int gr = nb + row;
      float4 v0 = make_float4(0.f, 0.f, 0.f, 0.f), v1 = v0;
      if (gr < N) {
        v0 = H4[(size_t)gr * 64 + k8 * 2];
        v1 = H4[(size_t)gr * 64 + k8 * 2 + 1];
      }
      float f[8] = {v0.x, v0.y, v0.z, v0.w, v1.x, v1.y, v1.z, v1.w};
      unsigned hi[8], lo[8];
#pragma unroll
      for (int j = 0; j < 8; ++j) {
        unsigned short hb = f2bf(f[j]);
        hi[j] = hb;
        lo[j] = f2bf(f[j] - bf2f(hb));
      }
      int slot = (k8 * 64 + row) ^ (k8 & 7);
      lds4[slot] = make_uint4(hi[0] | (hi[1] << 16), hi[2] | (hi[3] << 16),
                              hi[4] | (hi[5] << 16), hi[6] | (hi[7] << 16));
      lds4[2048 + slot] = make_uint4(lo[0] | (lo[1] << 16), lo[2] | (lo[3] << 16),
                                     lo[4] | (lo[5] << 16), lo[6] | (lo[7] << 16));
    }
  } else {   // bf16 input: exact, lo = 0 (skipped in MFMA loop)
    const uint4* __restrict__ H8 = (const uint4*)Hraw;
#pragma unroll
    for (int it = 0; it < 8; ++it) {
      int c = it * 256 + t;
      int row = c >> 5, k8 = c & 31;
      int gr = nb + row;
      uint4 v = make_uint4(0u, 0u, 0u, 0u);
      if (gr < N) v = H8[(size_t)gr * 32 + k8];
      lds4[(k8 * 64 + row) ^ (k8 & 7)] = v;
    }
  }
  __syncthreads();

  const int l = t & 63;
  const int wrow = (t >> 6) * 16;
  f32x4 acc[8];
#pragma unroll
  for (int ct = 0; ct < 8; ++ct) acc[ct] = (f32x4){0.f, 0.f, 0.f, 0.f};
  const uint4* __restrict__ Bh4 = (const uint4*)Bhi;
  const uint4* __restrict__ Bl4 = (const uint4*)Blo;
  if (dt) {
#pragma unroll 2
    for (int kt = 0; kt < 8; ++kt) {
      int k8 = kt * 4 + (l >> 4);
      int slot = (k8 * 64 + wrow + (l & 15)) ^ (k8 & 7);
      bf16x8 ah = as8(lds4[slot]);
      bf16x8 al = as8(lds4[2048 + slot]);
#pragma unroll
      for (int ct = 0; ct < 8; ++ct) {
        bf16x8 bh = as8(Bh4[(kt * 8 + ct) * 64 + l]);
        bf16x8 bl = as8(Bl4[(kt * 8 + ct) * 64 + l]);
        acc[ct] = __builtin_amdgcn_mfma_f32_16x16x32_bf16(ah, bh, acc[ct], 0, 0, 0);
        acc[ct] = __builtin_amdgcn_mfma_f32_16x16x32_bf16(ah, bl, acc[ct], 0, 0, 0);
        acc[ct] = __builtin_amdgcn_mfma_f32_16x16x32_bf16(al, bh, acc[ct], 0, 0, 0);
      }
    }
  } else {
#pragma unroll 2
    for (int kt = 0; kt < 8; ++kt) {
      int k8 = kt * 4 + (l >> 4);
      int slot = (k8 * 64 + wrow + (l & 15)) ^ (k8 & 7);
      bf16x8 ah = as8(lds4[slot]);
#pragma unroll
      for (int ct = 0; ct < 8; ++ct) {
        bf16x8 bh = as8(Bh4[(kt * 8 + ct) * 64 + l]);
        acc[ct] = __builtin_amdgcn_mfma_f32_16x16x32_bf16(ah, bh, acc[ct], 0, 0, 0);
      }
    }
  }
  // C/D layout: col = lane&15, row = (lane>>4)*4 + reg  [m89-verified]
#pragma unroll
  for (int ct = 0; ct < 8; ++ct) {
#pragma unroll
    for (int r = 0; r < 4; ++r) {
      int grow = nb + wrow + (l >> 4) * 4 + r;
      if (grow < N) Hproj[(size_t)grow * 128 + ct * 16 + (l & 15)] = acc[ct][r];
    }
  }
}

// ---- K2: per-node attention dots + msg base + fp16 copies --------------------
__global__ __launch_bounds__(256) void k_node(const float* __restrict__ Hproj,
                                              const float* __restrict__ af,   // [a_src(128)|a_dst(128)]
                                              const float* __restrict__ msgwf,
                                              float* __restrict__ s_src,
                                              float* __restrict__ s_dst,
                                              __half* __restrict__ msgb,
                                              __half* __restrict__ Hb, int N) {
  const int l = threadIdx.x & 63;
  const int wb = threadIdx.x >> 6;
  const int n = (blockIdx.x << 2) + wb;
  if (n >= N) return;
  const float* row = Hproj + (size_t)n * 128;
  float h0 = row[l], h1 = row[64 + l];
  Hb[(size_t)n * 128 + l]      = __float2half(h0);
  Hb[(size_t)n * 128 + 64 + l] = __float2half(h1);
  float p0 = h0 * af[l],       p1 = h1 * af[64 + l];
  float q0 = h0 * af[128 + l], q1 = h1 * af[192 + l];
#pragma unroll
  for (int off = 16; off; off >>= 1) {
    p0 += __shfl_xor(p0, off);
    p1 += __shfl_xor(p1, off);
    q0 += __shfl_xor(q0, off);
    q1 += __shfl_xor(q1, off);
  }
  if (l == 0)  { s_src[n*4+0] = p0; s_src[n*4+2] = p1; s_dst[n*4+0] = q0; s_dst[n*4+2] = q1; }
  if (l == 32) { s_src[n*4+1] = p0; s_src[n*4+3] = p1; s_dst[n*4+1] = q0; s_dst[n*4+3] = q1; }
  float t4 = h0 + __shfl_xor(h0, 32) + h1 + __shfl_xor(h1, 32);
  float hbar = 0.25f * t4;  // lanes 0..31: mean over heads at d=l
  if (l < DK) {
    float acc = 0.f;
#pragma unroll
    for (int d = 0; d < DK; ++d) acc += __shfl(hbar, d) * msgwf[l * DK + d];
    msgb[(size_t)n * DK + l] = __float2half(acc);
  }
}

// ---- K3: per-edge logits + LeakyReLU + per-head global max (no e_vals store) -
__global__ __launch_bounds__(256) void k_logits(const int* __restrict__ src,
                                                const int* __restrict__ dst,
                                                const void* __restrict__ sim1,
                                                const int* __restrict__ dflag,
                                                const float* __restrict__ s_src,
                                                const float* __restrict__ s_dst,
                                                unsigned* __restrict__ gmax, int E) {
  const int e = blockIdx.x * 256 + threadIdx.x;
  float m0 = -FLT_MAX, m1 = -FLT_MAX, m2 = -FLT_MAX, m3 = -FLT_MAX;
  if (e < E) {
    int s = src[e], d = dst[e];
    float4 ss = *(const float4*)(s_src + (size_t)s * 4);
    float4 sd = *(const float4*)(s_dst + (size_t)d * 4);
    float sv = (*dflag) ? ((const float*)sim1)[e] : bf2f(((const unsigned short*)sim1)[e]);
    float b = kBeta * sv;
    float e0 = ss.x + sd.x + b; e0 = (e0 >= 0.f) ? e0 : kNeg * e0;
    float e1 = ss.y + sd.y + b; e1 = (e1 >= 0.f) ? e1 : kNeg * e1;
    float e2 = ss.z + sd.z + b; e2 = (e2 >= 0.f) ? e2 : kNeg * e2;
    float e3 = ss.w + sd.w + b; e3 = (e3 >= 0.f) ? e3 : kNeg * e3;
    m0 = e0; m1 = e1; m2 = e2; m3 = e3;
  }
#pragma unroll
  for (int off = 32; off; off >>= 1) {
    m0 = fmaxf(m0, __shfl_xor(m0, off));
    m1 = fmaxf(m1, __shfl_xor(m1, off));
    m2 = fmaxf(m2, __shfl_xor(m2, off));
    m3 = fmaxf(m3, __shfl_xor(m3, off));
  }
  __shared__ float red[4][4];
  if ((threadIdx.x & 63) == 0) {
    int w = threadIdx.x >> 6;
    red[w][0] = m0; red[w][1] = m1; red[w][2] = m2; red[w][3] = m3;
  }
  __syncthreads();
  if (threadIdx.x < 4) {
    int h = threadIdx.x;
    float mm = fmaxf(fmaxf(red[0][h], red[1][h]), fmaxf(red[2][h], red[3][h]));
    atomicMax(gmax + h, fkey(mm));
  }
}

// ---- K4: msg_base gather (fp16 table, L2-resident; float2 coalesced writes) --
__global__ __launch_bounds__(256) void k_msg(const int* __restrict__ src,
                                             const __half2* __restrict__ msgb2,
                                             const int* __restrict__ dflag,
                                             void* __restrict__ d_out,
                                             int N, int E) {
  long long tid = (long long)blockIdx.x * 256 + threadIdx.x;
  if (tid >= (long long)E * 16) return;
  int e = (int)(tid >> 4), jp = (int)(tid & 15);
  __half2 hv = msgb2[(size_t)src[e] * 16 + jp];
  float2 f = __half22float2(hv);
  const size_t msg_off = (size_t)N * 128 + (size_t)E;
  if (*dflag) {
    *(float2*)&((float*)d_out)[msg_off + (size_t)e * 32 + 2 * jp] = f;
  } else {
    __hip_bfloat162 b = __float22bfloat162_rn(f);
    *(__hip_bfloat162*)((__hip_bfloat16*)d_out + msg_off + (size_t)e * 32 + 2 * jp) = b;
  }
}

// ---- K5: wave-per-node CSR gather: recomputed logits, fp16 Hb gather ---------
__global__ __launch_bounds__(256) void k_out(const int* __restrict__ row_ptr,
                                             const int* __restrict__ eidx,
                                             const int* __restrict__ src,
                                             const void* __restrict__ sim1,
                                             const float* __restrict__ s_src,
                                             const float* __restrict__ s_dst,
                                             const unsigned* __restrict__ gmax,
                                             const unsigned* __restrict__ Hb_u,
                                             const int* __restrict__ dflag,
                                             void* __restrict__ d_out, int N, int E) {
  const int n = (int)((blockIdx.x * 256 + threadIdx.x) >> 6);
  const int l = threadIdx.x & 63;
  if (n >= N) return;
  const int beg = row_ptr[n];
  const int deg = row_ptr[n + 1] - beg;
  const int dt = *dflag;
  const float m0 = funkey(gmax[0]), m1 = funkey(gmax[1]);
  const float m2 = funkey(gmax[2]), m3 = funkey(gmax[3]);
  const float4 sd = *(const float4*)(s_dst + (size_t)n * 4);  // wave-uniform
  const size_t alpha_off = (size_t)N * 128;
  float accx = 0.f, accy = 0.f;
  float4 dn = make_float4(0.f, 0.f, 0.f, 0.f);
  int eid = 0, s = 0;
  float4 ev = make_float4(0.f, 0.f, 0.f, 0.f);
  const bool small = (deg <= 64);
  if (small) {
    if (l < deg) {
      eid = eidx[beg + l];
      s = src[eid];
      float4 ss = *(const float4*)(s_src + (size_t)s * 4);
      float sv = dt ? ((const float*)sim1)[eid] : bf2f(((const unsigned short*)sim1)[eid]);
      float e0 = ss.x + sd.x + sv; e0 = (e0 >= 0.f) ? e0 : kNeg * e0;
      float e1 = ss.y + sd.y + sv; e1 = (e1 >= 0.f) ? e1 : kNeg * e1;
      float e2 = ss.z + sd.z + sv; e2 = (e2 >= 0.f) ? e2 : kNeg * e2;
      float e3 = ss.w + sd.w + sv; e3 = (e3 >= 0.f) ? e3 : kNeg * e3;
      ev = make_float4(expf(e0 - m0), expf(e1 - m1), expf(e2 - m2), expf(e3 - m3));
      dn = ev;
    }
  } else {
    for (int base = 0; base < deg; base += 64) {
      if (base + l < deg) {
        int e2i = eidx[beg + base + l];
        int s2 = src[e2i];
        float4 ss = *(const float4*)(s_src + (size_t)s2 * 4);
        float sv = dt ? ((const float*)sim1)[e2i] : bf2f(((const unsigned short*)sim1)[e2i]);
        float e0 = ss.x + sd.x + sv; e0 = (e0 >= 0.f) ? e0 : kNeg * e0;
        float e1 = ss.y + sd.y + sv; e1 = (e1 >= 0.f) ? e1 : kNeg * e1;
        float e2 = ss.z + sd.z + sv; e2 = (e2 >= 0.f) ? e2 : kNeg * e2;
        float e3 = ss.w + sd.w + sv; e3 = (e3 >= 0.f) ? e3 : kNeg * e3;
        dn.x += expf(e0 - m0); dn.y += expf(e1 - m1);
        dn.z += expf(e2 - m2); dn.w += expf(e3 - m3);
      }
    }
  }
#pragma unroll
  for (int off = 32; off; off >>= 1) {
    dn.x += __shfl_xor(dn.x, off);
    dn.y += __shfl_xor(dn.y, off);
    dn.z += __shfl_xor(dn.z, off);
    dn.w += __shfl_xor(dn.w, off);
  }
  const float i0 = 1.f / (dn.x + kEps), i1 = 1.f / (dn.y + kEps);
  const float i2 = 1.f / (dn.z + kEps), i3 = 1.f / (dn.w + kEps);
  const float myinv = (l < 32) ? ((l < 16) ? i0 : i1) : ((l < 48) ? i2 : i3);
  if (small) {
    if (l < deg) {
      float am = 0.25f * (ev.x * i0 + ev.y * i1 + ev.z * i2 + ev.w * i3);
      if (dt) ((float*)d_out)[alpha_off + eid] = am;
      else    ((__hip_bfloat16*)d_out)[alpha_off + eid] = __float2bfloat16(am);
    }
    for (int i = 0; i < deg; ++i) {
      int si = __shfl(s, i);
      float ax = __shfl(ev.x, i), ay = __shfl(ev.y, i);
      float az = __shfl(ev.z, i), aw = __shfl(ev.w, i);
      float aa = ((l < 32) ? ((l < 16) ? ax : ay) : ((l < 48) ? az : aw)) * myinv;
      unsigned u = Hb_u[(size_t)si * 64 + l];
      float2 f = __half22float2(*(const __half2*)&u);
      accx += aa * f.x;
      accy += aa * f.y;
    }
  } else {
    for (int base = 0; base < deg; base += 64) {
      int cnt = min(64, deg - base);
      int eid2 = 0, s2 = 0;
      float4 e2v = make_float4(0.f, 0.f, 0.f, 0.f);
      if (l < cnt) {
        eid2 = eidx[beg + base + l];
        s2 = src[eid2];
        float4 ss = *(const float4*)(s_src + (size_t)s2 * 4);
        float sv = dt ? ((const float*)sim1)[eid2] : bf2f(((const unsigned short*)sim1)[eid2]);
        float e0 = ss.x + sd.x + sv; e0 = (e0 >= 0.f) ? e0 : kNeg * e0;
        float e1 = ss.y + sd.y + sv; e1 = (e1 >= 0.f) ? e1 : kNeg * e1;
        float e2 = ss.z + sd.z + sv; e2 = (e2 >= 0.f) ? e2 : kNeg * e2;
        float e3 = ss.w + sd.w + sv; e3 = (e3 >= 0.f) ? e3 : kNeg * e3;
        e2v = make_float4(expf(e0 - m0), expf(e1 - m1), expf(e2 - m2), expf(e3 - m3));
        float am = 0.25f * (e2v.x * i0 + e2v.y * i1 + e2v.z * i2 + e2v.w * i3);
        if (dt) ((float*)d_out)[alpha_off + eid2] = am;
        else    ((__hip_bfloat16*)d_out)[alpha_off + eid2] = __float2bfloat16(am);
      }
      for (int i = 0; i < cnt; ++i) {
        int si = __shfl(s2, i);
        float ax = __shfl(e2v.x, i), ay = __shfl(e2v.y, i);
        float az = __shfl(e2v.z, i), aw = __shfl(e2v.w, i);
        float aa = ((l < 32) ? ((l < 16) ? ax : ay) : ((l < 48) ? az : aw)) * myinv;
        unsigned u = Hb_u[(size_t)si * 64 + l];
        float2 f = __half22float2(*(const __half2*)&u);
        accx += aa * f.x;
        accy += aa * f.y;
      }
    }
  }
  if (dt) {
    *(float2*)&((float*)d_out)[(size_t)n * 128 + 2 * l] = make_float2(accx, accy);
  } else {
    __hip_bfloat162 b = __float22bfloat162_rn(make_float2(accx, accy));
    *(__hip_bfloat162*)((__hip_bfloat16*)d_out + (size_t)n * 128 + 2 * l) = b;
  }
}

extern "C" void kernel_launch(void* const* d_in, const int* in_sizes, int n_in,
                              void* d_out, int out_size, void* d_ws, size_t ws_size,
                              hipStream_t stream) {
  const void* H     = d_in[0];
  const int*  ei    = (const int*)d_in[1];
  const void* sim1  = d_in[2];
  const void* W     = d_in[3];
  const void* a_src = d_in[4];
  const void* a_dst = d_in[5];
  const void* msg_w = d_in[6];
  const int N = in_sizes[0] / 256;
  const int E = in_sizes[2];
  const int NB = (N + 255) / 256;  // scan blocks (<=1024 supported)

  char* base     = (char*)d_ws;
  float* Hproj   = (float*)base;  base += (size_t)N * 128 * 4;
  float* s_src   = (float*)base;  base += (size_t)N * 4 * 4;
  float* s_dst   = (float*)base;  base += (size_t)N * 4 * 4;
  __half* msgb   = (__half*)base; base += (size_t)N * DK * 2;
  __half* Hb     = (__half*)base; base += (size_t)N * 128 * 2;
  unsigned short* Bhi = (unsigned short*)base; base += 32768 * 2;  // 64 KB
  unsigned short* Blo = (unsigned short*)base; base += 32768 * 2;  // 64 KB
  int* deg       = (int*)base;    base += (size_t)N * 4;   // <- zeroed from here
  unsigned* gmax = (unsigned*)base; base += 4 * 4;
  int* eflag     = (int*)base;    base += 4;
  int* dflag     = (int*)base;    base += 4;               // <- zeroed to here
  int* row_ptr   = (int*)base;    base += (size_t)(N + 1) * 4;
  int* cursor    = (int*)base;    base += (size_t)N * 4;
  int* bsum      = (int*)base;    base += 1024 * 4;
  int* eidx      = (int*)base;    base += (size_t)E * 4;
  int* src_i     = (int*)base;    base += (size_t)E * 4;
  int* dst_i     = (int*)base;    base += (size_t)E * 4;
  float* af      = (float*)base;  base += 256 * 4;
  float* msgwf   = (float*)base;  base += 1024 * 4;

  hipMemsetAsync(deg, 0, (size_t)(N + 6) * sizeof(int), stream);

  k_detect<<<512, 256, 0, stream>>>(ei, (const unsigned*)H, eflag, dflag, E, 131072);
  k_cvt<<<(E + 255) / 256, 256, 0, stream>>>(ei, eflag, src_i, dst_i, deg, E);
  k_wpack<<<128, 256, 0, stream>>>(W, Bhi, Blo, dflag, 128 * 256);
  k_params<<<5, 256, 0, stream>>>(a_src, a_dst, msg_w, af, msgwf, dflag);
  k_proj<<<(N + 63) / 64, 256, 0, stream>>>(H, Bhi, Blo, dflag, Hproj, N);
  k_scan1<<<NB, 256, 0, stream>>>(deg, bsum, N);
  k_scan2<<<1, 1024, 0, stream>>>(bsum, NB);
  k_scan3<<<NB, 256, 0, stream>>>(deg, bsum, row_ptr, cursor, N);
  k_fill<<<(E + 255) / 256, 256, 0, stream>>>(dst_i, cursor, eidx, E);
  k_node<<<(N + 3) / 4, 256, 0, stream>>>(Hproj, af, msgwf, s_src, s_dst, msgb, Hb, N);
  k_logits<<<(E + 255) / 256, 256, 0, stream>>>(src_i, dst_i, sim1, dflag, s_src, s_dst,
                                                gmax, E);
  k_msg<<<(int)(((long long)E * 16 + 255) / 256), 256, 0, stream>>>(
      src_i, (const __half2*)msgb, dflag, d_out, N, E);
  k_out<<<(int)(((size_t)N * 64 + 255) / 256), 256, 0, stream>>>(
      row_ptr, eidx, src_i, sim1, s_src, s_dst, gmax, (const unsigned*)Hb, dflag,
      d_out, N, E);
}

// Round 6
// 477.717 us; speedup vs baseline: 2.0813x; 1.0128x over previous
//
#include <hip/hip_runtime.h>
#include <hip/hip_bf16.h>
#include <hip/hip_fp16.h>
#include <float.h>

#define HEADS 4
#define DK 32

static constexpr float kBeta = 1.0f;
static constexpr float kNeg  = 0.2f;
static constexpr float kEps  = 1e-12f;

typedef __bf16 bf16x8 __attribute__((ext_vector_type(8)));
typedef float  f32x4  __attribute__((ext_vector_type(4)));

__device__ __forceinline__ float bf2f(unsigned short v) {
  return __uint_as_float((unsigned)v << 16);
}
// round-to-nearest-even f32 -> bf16 bits
__device__ __forceinline__ unsigned short f2bf(float f) {
  unsigned u = __float_as_uint(f);
  unsigned r = u + 0x7FFFu + ((u >> 16) & 1u);
  return (unsigned short)(r >> 16);
}
// order-preserving float <-> uint key for atomicMax
__device__ __forceinline__ unsigned fkey(float x) {
  unsigned u = __float_as_uint(x);
  return (u & 0x80000000u) ? ~u : (u | 0x80000000u);
}
__device__ __forceinline__ float funkey(unsigned k) {
  unsigned u = (k & 0x80000000u) ? (k & 0x7fffffffu) : ~k;
  return __uint_as_float(u);
}
__device__ __forceinline__ bf16x8 as8(uint4 v) {
  union { uint4 u; bf16x8 b; } x; x.u = v; return x.b;
}

// ---- K0a: fused detect: edge layout (int64 -> odd words 0) + float dtype -----
__global__ __launch_bounds__(256) void k_detect(const int* __restrict__ ei32,
                                                const unsigned* __restrict__ Hw,
                                                int* __restrict__ eflag,
                                                int* __restrict__ dflag,
                                                int E, int nw) {
  int i = blockIdx.x * 256 + threadIdx.x;
  if (i < 4096 && 2 * i + 1 < 2 * E && ei32[2 * i + 1] != 0) atomicOr(eflag, 1);
  if (i < nw && ((Hw[i] >> 7) & 0xFFu) == 0xFFu) atomicOr(dflag, 1);
}

// ---- K0c: normalize edge index into int32 src/dst + degree histogram ---------
__global__ __launch_bounds__(256) void k_cvt(const int* __restrict__ ei32,
                                             const int* __restrict__ eflag,
                                             int* __restrict__ src_i,
                                             int* __restrict__ dst_i,
                                             int* __restrict__ deg, int E) {
  int i = blockIdx.x * 256 + threadIdx.x;
  if (i >= E) return;
  int s, d;
  if (*eflag) { s = ei32[i];     d = ei32[E + i]; }
  else        { s = ei32[2 * i]; d = ei32[2 * E + 2 * i]; }
  src_i[i] = s;
  dst_i[i] = d;
  atomicAdd(deg + d, 1);
}

// ---- K0d: W -> MFMA B-fragment pack (hi/lo bf16 split) + small params --------
// blocks 0..127: W pack. blocks 128..132: a_src|a_dst|msg_lin_w convert.
__global__ __launch_bounds__(256) void k_wparams(const void* __restrict__ in,
                                                 unsigned short* __restrict__ Bhi,
                                                 unsigned short* __restrict__ Blo,
                                                 const void* __restrict__ a_src,
                                                 const void* __restrict__ a_dst,
                                                 const void* __restrict__ msg_w,
                                                 float* __restrict__ af,
                                                 float* __restrict__ msgwf,
                                                 const int* __restrict__ dflag) {
  const int dt = *dflag;
  if (blockIdx.x < 128) {
    int i = blockIdx.x * 256 + threadIdx.x;  // i = r*256 + c, r: out-col, c: k
    int r = i >> 8, c = i & 255;
    float v = dt ? ((const float*)in)[i] : bf2f(((const unsigned short*)in)[i]);
    unsigned short hb = f2bf(v);
    unsigned short lb = f2bf(v - bf2f(hb));
    int kt = c >> 5, ct = r >> 4;
    int lane = (((c >> 3) & 3) << 4) | (r & 15);
    int idx = ((kt * 8 + ct) * 64 + lane) * 8 + (c & 7);
    Bhi[idx] = hb;
    Blo[idx] = lb;
  } else {
    int i = (blockIdx.x - 128) * 256 + threadIdx.x;  // [0, 1280)
    if (i < 128) {
      af[i] = dt ? ((const float*)a_src)[i] : bf2f(((const unsigned short*)a_src)[i]);
    } else if (i < 256) {
      int j = i - 128;
      af[i] = dt ? ((const float*)a_dst)[j] : bf2f(((const unsigned short*)a_dst)[j]);
    } else if (i < 1280) {
      int j = i - 256;
      msgwf[j] = dt ? ((const float*)msg_w)[j] : bf2f(((const unsigned short*)msg_w)[j]);
    }
  }
}

// ---- K0e: 3-phase device-wide exclusive scan of deg --------------------------
__global__ __launch_bounds__(256) void k_scan1(const int* __restrict__ deg,
                                               int* __restrict__ bsum, int N) {
  const int t = threadIdx.x;
  int i = blockIdx.x * 256 + t;
  int v = (i < N) ? deg[i] : 0;
#pragma unroll
  for (int off = 32; off; off >>= 1) v += __shfl_xor(v, off);
  __shared__ int red[4];
  if ((t & 63) == 0) red[t >> 6] = v;
  __syncthreads();
  if (t == 0) bsum[blockIdx.x] = red[0] + red[1] + red[2] + red[3];
}
__global__ __launch_bounds__(1024) void k_scan2(int* __restrict__ bsum, int nb) {
  __shared__ int part[1024];
  const int t = threadIdx.x;
  part[t] = (t < nb) ? bsum[t] : 0;
  __syncthreads();
  int own = part[t];
  for (int off = 1; off < 1024; off <<= 1) {
    int v = (t >= off) ? part[t - off] : 0;
    __syncthreads();
    part[t] += v;
    __syncthreads();
  }
  if (t < nb) bsum[t] = part[t] - own;  // exclusive block offset
}
__global__ __launch_bounds__(256) void k_scan3(const int* __restrict__ deg,
                                               const int* __restrict__ bsum,
                                               int* __restrict__ row_ptr,
                                               int* __restrict__ cursor, int N) {
  __shared__ int part[256];
  const int t = threadIdx.x;
  int i = blockIdx.x * 256 + t;
  int v = (i < N) ? deg[i] : 0;
  part[t] = v;
  __syncthreads();
  for (int off = 1; off < 256; off <<= 1) {
    int x = (t >= off) ? part[t - off] : 0;
    __syncthreads();
    part[t] += x;
    __syncthreads();
  }
  int excl = part[t] - v + bsum[blockIdx.x];
  if (i < N) {
    row_ptr[i] = excl;
    cursor[i]  = excl;
    if (i == N - 1) row_ptr[N] = excl + v;
  }
}

// ---- K1: H_proj = H @ W.T via MFMA + fused per-node epilogue (ex-k_node) -----
__global__ __launch_bounds__(256) void k_proj(const void* __restrict__ Hraw,
                                              const unsigned short* __restrict__ Bhi,
                                              const unsigned short* __restrict__ Blo,
                                              const int* __restrict__ dflag,
                                              const float* __restrict__ af,
                                              const float* __restrict__ msgwf,
                                              float* __restrict__ s_src,
                                              float* __restrict__ s_dst,
                                              __half* __restrict__ msgb,
                                              __half* __restrict__ Hb, int N) {
  __shared__ uint4 lds4[4096];  // staging: [0,2048) A_hi, [2048,4096) A_lo
  float* ldsF = (float*)lds4;   // epilogue: [64][132] f32 rows (33 KB, reused)
  const int t = threadIdx.x;
  const int nb = blockIdx.x * 64;
  const int dt = *dflag;
  if (dt) {  // fp32 input: split into hi+lo bf16
    const float4* __restrict__ H4 = (const float4*)Hraw;
#pragma unroll
    for (int it = 0; it < 8; ++it) {
      int c = it * 256 + t;
      int row = c >> 5, k8 = c & 31;
      int gr = nb + row;
      float4 v0 = make_float4(0.f, 0.f, 0.f, 0.f), v1 = v0;
      if (gr < N) {
        v0 = H4[(size_t)gr * 64 + k8 * 2];
        v1 = H4[(size_t)gr * 64 + k8 * 2 + 1];
      }
      float f[8] = {v0.x, v0.y, v0.z, v0.w, v1.x, v1.y, v1.z, v1.w};
      unsigned hi[8], lo[8];
#pragma unroll
      for (int j = 0; j < 8; ++j) {
        unsigned short hb = f2bf(f[j]);
        hi[j] = hb;
        lo[j] = f2bf(f[j] - bf2f(hb));
      }
      int slot = (k8 * 64 + row) ^ (k8 & 7);
      lds4[slot] = make_uint4(hi[0] | (hi[1] << 16), hi[2] | (hi[3] << 16),
                              hi[4] | (hi[5] << 16), hi[6] | (hi[7] << 16));
      lds4[2048 + slot] = make_uint4(lo[0] | (lo[1] << 16), lo[2] | (lo[3] << 16),
                                     lo[4] | (lo[5] << 16), lo[6] | (lo[7] << 16));
    }
  } else {   // bf16 input: exact, lo = 0 (skipped)
    const uint4* __restrict__ H8 = (const uint4*)Hraw;
#pragma unroll
    for (int it = 0; it < 8; ++it) {
      int c = it * 256 + t;
      int row = c >> 5, k8 = c & 31;
      int gr = nb + row;
      uint4 v = make_uint4(0u, 0u, 0u, 0u);
      if (gr < N) v = H8[(size_t)gr * 32 + k8];
      lds4[(k8 * 64 + row) ^ (k8 & 7)] = v;
    }
  }
  __syncthreads();

  const int l = t & 63;
  const int wrow = (t >> 6) * 16;
  f32x4 acc[8];
#pragma unroll
  for (int ct = 0; ct < 8; ++ct) acc[ct] = (f32x4){0.f, 0.f, 0.f, 0.f};
  const uint4* __restrict__ Bh4 = (const uint4*)Bhi;
  const uint4* __restrict__ Bl4 = (const uint4*)Blo;
  if (dt) {
#pragma unroll 2
    for (int kt = 0; kt < 8; ++kt) {
      int k8 = kt * 4 + (l >> 4);
      int slot = (k8 * 64 + wrow + (l & 15)) ^ (k8 & 7);
      bf16x8 ah = as8(lds4[slot]);
      bf16x8 al = as8(lds4[2048 + slot]);
#pragma unroll
      for (int ct = 0; ct < 8; ++ct) {
        bf16x8 bh = as8(Bh4[(kt * 8 + ct) * 64 + l]);
        bf16x8 bl = as8(Bl4[(kt * 8 + ct) * 64 + l]);
        acc[ct] = __builtin_amdgcn_mfma_f32_16x16x32_bf16(ah, bh, acc[ct], 0, 0, 0);
        acc[ct] = __builtin_amdgcn_mfma_f32_16x16x32_bf16(ah, bl, acc[ct], 0, 0, 0);
        acc[ct] = __builtin_amdgcn_mfma_f32_16x16x32_bf16(al, bh, acc[ct], 0, 0, 0);
      }
    }
  } else {
#pragma unroll 2
    for (int kt = 0; kt < 8; ++kt) {
      int k8 = kt * 4 + (l >> 4);
      int slot = (k8 * 64 + wrow + (l & 15)) ^ (k8 & 7);
      bf16x8 ah = as8(lds4[slot]);
#pragma unroll
      for (int ct = 0; ct < 8; ++ct) {
        bf16x8 bh = as8(Bh4[(kt * 8 + ct) * 64 + l]);
        acc[ct] = __builtin_amdgcn_mfma_f32_16x16x32_bf16(ah, bh, acc[ct], 0, 0, 0);
      }
    }
  }
  __syncthreads();  // staging reads done; reuse LDS as f32 row buffer
  // C/D layout: col = lane&15, row = (lane>>4)*4 + reg  [m89-verified]
#pragma unroll
  for (int ct = 0; ct < 8; ++ct)
#pragma unroll
    for (int r = 0; r < 4; ++r)
      ldsF[(wrow + (l >> 4) * 4 + r) * 132 + ct * 16 + (l & 15)] = acc[ct][r];
  __syncthreads();
  // per-node epilogue: wave handles rows wrow..wrow+15
  for (int i = 0; i < 16; ++i) {
    int row = wrow + i, n = nb + row;
    if (n >= N) break;
    float h0 = ldsF[row * 132 + l], h1 = ldsF[row * 132 + 64 + l];
    Hb[(size_t)n * 128 + l]      = __float2half(h0);
    Hb[(size_t)n * 128 + 64 + l] = __float2half(h1);
    float p0 = h0 * af[l],       p1 = h1 * af[64 + l];
    float q0 = h0 * af[128 + l], q1 = h1 * af[192 + l];
#pragma unroll
    for (int off = 16; off; off >>= 1) {
      p0 += __shfl_xor(p0, off);
      p1 += __shfl_xor(p1, off);
      q0 += __shfl_xor(q0, off);
      q1 += __shfl_xor(q1, off);
    }
    if (l == 0)  { s_src[n*4+0] = p0; s_src[n*4+2] = p1; s_dst[n*4+0] = q0; s_dst[n*4+2] = q1; }
    if (l == 32) { s_src[n*4+1] = p0; s_src[n*4+3] = p1; s_dst[n*4+1] = q0; s_dst[n*4+3] = q1; }
    float t4 = h0 + __shfl_xor(h0, 32) + h1 + __shfl_xor(h1, 32);
    float hbar = 0.25f * t4;  // lanes 0..31: mean over heads at d=l
    if (l < DK) {
      float acc2 = 0.f;
#pragma unroll
      for (int d = 0; d < DK; ++d) acc2 += __shfl(hbar, d) * msgwf[l * DK + d];
      msgb[(size_t)n * DK + l] = __float2half(acc2);
    }
  }
}

// ---- K3: CSR fill + (src,sim) pack + per-head global max (ex fill+logits) ----
__global__ __launch_bounds__(256) void k_fillog(const int* __restrict__ src,
                                                const int* __restrict__ dstv,
                                                const void* __restrict__ sim1,
                                                const int* __restrict__ dflag,
                                                const float* __restrict__ s_src,
                                                const float* __restrict__ s_dst,
                                                int* __restrict__ cursor,
                                                int2* __restrict__ pack,
                                                unsigned* __restrict__ gmax, int E) {
  const int e = blockIdx.x * 256 + threadIdx.x;
  float m0 = -FLT_MAX, m1 = -FLT_MAX, m2 = -FLT_MAX, m3 = -FLT_MAX;
  if (e < E) {
    int s = src[e], d = dstv[e];
    float sv = (*dflag) ? ((const float*)sim1)[e] : bf2f(((const unsigned short*)sim1)[e]);
    int pos = atomicAdd(cursor + d, 1);
    pack[pos] = make_int2(s, __float_as_int(sv));
    float4 ss = *(const float4*)(s_src + (size_t)s * 4);
    float4 sd = *(const float4*)(s_dst + (size_t)d * 4);
    float b = kBeta * sv;
    float e0 = ss.x + sd.x + b; e0 = (e0 >= 0.f) ? e0 : kNeg * e0;
    float e1 = ss.y + sd.y + b; e1 = (e1 >= 0.f) ? e1 : kNeg * e1;
    float e2 = ss.z + sd.z + b; e2 = (e2 >= 0.f) ? e2 : kNeg * e2;
    float e3 = ss.w + sd.w + b; e3 = (e3 >= 0.f) ? e3 : kNeg * e3;
    m0 = e0; m1 = e1; m2 = e2; m3 = e3;
  }
#pragma unroll
  for (int off = 32; off; off >>= 1) {
    m0 = fmaxf(m0, __shfl_xor(m0, off));
    m1 = fmaxf(m1, __shfl_xor(m1, off));
    m2 = fmaxf(m2, __shfl_xor(m2, off));
    m3 = fmaxf(m3, __shfl_xor(m3, off));
  }
  __shared__ float red[4][4];
  if ((threadIdx.x & 63) == 0) {
    int w = threadIdx.x >> 6;
    red[w][0] = m0; red[w][1] = m1; red[w][2] = m2; red[w][3] = m3;
  }
  __syncthreads();
  if (threadIdx.x < 4) {
    int h = threadIdx.x;
    float mm = fmaxf(fmaxf(red[0][h], red[1][h]), fmaxf(red[2][h], red[3][h]));
    atomicMax(gmax + h, fkey(mm));
  }
}

// ---- K5: wave-per-node CSR gather: denom + out rows (no alpha scatter) -------
__global__ __launch_bounds__(256) void k_out(const int* __restrict__ row_ptr,
                                             const int2* __restrict__ pack,
                                             const float* __restrict__ s_src,
                                             const float* __restrict__ s_dst,
                                             const unsigned* __restrict__ gmax,
                                             const unsigned* __restrict__ Hb_u,
                                             const int* __restrict__ dflag,
                                             float* __restrict__ denom,
                                             void* __restrict__ d_out, int N) {
  const int n = (int)((blockIdx.x * 256 + threadIdx.x) >> 6);
  const int l = threadIdx.x & 63;
  if (n >= N) return;
  const int beg = row_ptr[n];
  const int deg = row_ptr[n + 1] - beg;
  const int dt = *dflag;
  const float m0 = funkey(gmax[0]), m1 = funkey(gmax[1]);
  const float m2 = funkey(gmax[2]), m3 = funkey(gmax[3]);
  const float4 sd = *(const float4*)(s_dst + (size_t)n * 4);  // wave-uniform
  float accx = 0.f, accy = 0.f;
  float4 dn = make_float4(0.f, 0.f, 0.f, 0.f);
  int s = 0;
  float4 ev = make_float4(0.f, 0.f, 0.f, 0.f);
  const bool small = (deg <= 64);
  if (small) {
    if (l < deg) {
      int2 p = pack[beg + l];
      s = p.x;
      float sv = __int_as_float(p.y);
      float4 ss = *(const float4*)(s_src + (size_t)s * 4);
      float e0 = ss.x + sd.x + sv; e0 = (e0 >= 0.f) ? e0 : kNeg * e0;
      float e1 = ss.y + sd.y + sv; e1 = (e1 >= 0.f) ? e1 : kNeg * e1;
      float e2 = ss.z + sd.z + sv; e2 = (e2 >= 0.f) ? e2 : kNeg * e2;
      float e3 = ss.w + sd.w + sv; e3 = (e3 >= 0.f) ? e3 : kNeg * e3;
      ev = make_float4(expf(e0 - m0), expf(e1 - m1), expf(e2 - m2), expf(e3 - m3));
      dn = ev;
    }
  } else {
    for (int base = 0; base < deg; base += 64) {
      if (base + l < deg) {
        int2 p = pack[beg + base + l];
        float sv = __int_as_float(p.y);
        float4 ss = *(const float4*)(s_src + (size_t)p.x * 4);
        float e0 = ss.x + sd.x + sv; e0 = (e0 >= 0.f) ? e0 : kNeg * e0;
        float e1 = ss.y + sd.y + sv; e1 = (e1 >= 0.f) ? e1 : kNeg * e1;
        float e2 = ss.z + sd.z + sv; e2 = (e2 >= 0.f) ? e2 : kNeg * e2;
        float e3 = ss.w + sd.w + sv; e3 = (e3 >= 0.f) ? e3 : kNeg * e3;
        dn.x += expf(e0 - m0); dn.y += expf(e1 - m1);
        dn.z += expf(e2 - m2); dn.w += expf(e3 - m3);
      }
    }
  }
#pragma unroll
  for (int off = 32; off; off >>= 1) {
    dn.x += __shfl_xor(dn.x, off);
    dn.y += __shfl_xor(dn.y, off);
    dn.z += __shfl_xor(dn.z, off);
    dn.w += __shfl_xor(dn.w, off);
  }
  if (l == 0) *(float4*)(denom + (size_t)n * 4) = make_float4(dn.x, dn.y, dn.z, dn.w);
  const float i0 = 1.f / (dn.x + kEps), i1 = 1.f / (dn.y + kEps);
  const float i2 = 1.f / (dn.z + kEps), i3 = 1.f / (dn.w + kEps);
  const float myinv = (l < 32) ? ((l < 16) ? i0 : i1) : ((l < 48) ? i2 : i3);
  if (small) {
    for (int i = 0; i < deg; ++i) {
      int si = __shfl(s, i);
      float ax = __shfl(ev.x, i), ay = __shfl(ev.y, i);
      float az = __shfl(ev.z, i), aw = __shfl(ev.w, i);
      float aa = ((l < 32) ? ((l < 16) ? ax : ay) : ((l < 48) ? az : aw)) * myinv;
      unsigned u = Hb_u[(size_t)si * 64 + l];
      float2 f = __half22float2(*(const __half2*)&u);
      accx += aa * f.x;
      accy += aa * f.y;
    }
  } else {
    for (int base = 0; base < deg; base += 64) {
      int cnt = min(64, deg - base);
      int s2 = 0;
      float4 e2v = make_float4(0.f, 0.f, 0.f, 0.f);
      if (l < cnt) {
        int2 p = pack[beg + base + l];
        s2 = p.x;
        float sv = __int_as_float(p.y);
        float4 ss = *(const float4*)(s_src + (size_t)s2 * 4);
        float e0 = ss.x + sd.x + sv; e0 = (e0 >= 0.f) ? e0 : kNeg * e0;
        float e1 = ss.y + sd.y + sv; e1 = (e1 >= 0.f) ? e1 : kNeg * e1;
        float e2 = ss.z + sd.z + sv; e2 = (e2 >= 0.f) ? e2 : kNeg * e2;
        float e3 = ss.w + sd.w + sv; e3 = (e3 >= 0.f) ? e3 : kNeg * e3;
        e2v = make_float4(expf(e0 - m0), expf(e1 - m1), expf(e2 - m2), expf(e3 - m3));
      }
      for (int i = 0; i < cnt; ++i) {
        int si = __shfl(s2, i);
        float ax = __shfl(e2v.x, i), ay = __shfl(e2v.y, i);
        float az = __shfl(e2v.z, i), aw = __shfl(e2v.w, i);
        float aa = ((l < 32) ? ((l < 16) ? ax : ay) : ((l < 48) ? az : aw)) * myinv;
        unsigned u = Hb_u[(size_t)si * 64 + l];
        float2 f = __half22float2(*(const __half2*)&u);
        accx += aa * f.x;
        accy += aa * f.y;
      }
    }
  }
  if (dt) {
    *(float2*)&((float*)d_out)[(size_t)n * 128 + 2 * l] = make_float2(accx, accy);
  } else {
    __hip_bfloat162 b = __float22bfloat162_rn(make_float2(accx, accy));
    *(__hip_bfloat162*)((__hip_bfloat16*)d_out + (size_t)n * 128 + 2 * l) = b;
  }
}

// ---- K6: per-edge epilogue: msg gather + alpha (original order, coalesced) ---
__global__ __launch_bounds__(256) void k_edge(const int* __restrict__ src,
                                              const int* __restrict__ dstv,
                                              const void* __restrict__ sim1,
                                              const int* __restrict__ dflag,
                                              const float* __restrict__ s_src,
                                              const float* __restrict__ s_dst,
                                              const float* __restrict__ denom,
                                              const unsigned* __restrict__ gmax,
                                              const __half2* __restrict__ msgb2,
                                              void* __restrict__ d_out,
                                              int N, int E) {
  long long tid = (long long)blockIdx.x * 256 + threadIdx.x;
  if (tid >= (long long)E * 16) return;
  int e = (int)(tid >> 4), jp = (int)(tid & 15);
  const int dt = *dflag;
  int s = src[e];
  __half2 hv = msgb2[(size_t)s * 16 + jp];
  float2 f = __half22float2(hv);
  const size_t alpha_off = (size_t)N * 128;
  const size_t msg_off = alpha_off + (size_t)E;
  if (dt) {
    *(float2*)&((float*)d_out)[msg_off + (size_t)e * 32 + 2 * jp] = f;
  } else {
    __hip_bfloat162 b = __float22bfloat162_rn(f);
    *(__hip_bfloat162*)((__hip_bfloat16*)d_out + msg_off + (size_t)e * 32 + 2 * jp) = b;
  }
  if (jp == 0) {
    int d = dstv[e];
    float sv = dt ? ((const float*)sim1)[e] : bf2f(((const unsigned short*)sim1)[e]);
    float4 ss = *(const float4*)(s_src + (size_t)s * 4);
    float4 sd = *(const float4*)(s_dst + (size_t)d * 4);
    float4 dn = *(const float4*)(denom + (size_t)d * 4);
    float m0 = funkey(gmax[0]), m1 = funkey(gmax[1]);
    float m2 = funkey(gmax[2]), m3 = funkey(gmax[3]);
    float b = kBeta * sv;
    float e0 = ss.x + sd.x + b; e0 = (e0 >= 0.f) ? e0 : kNeg * e0;
    float e1 = ss.y + sd.y + b; e1 = (e1 >= 0.f) ? e1 : kNeg * e1;
    float e2 = ss.z + sd.z + b; e2 = (e2 >= 0.f) ? e2 : kNeg * e2;
    float e3 = ss.w + sd.w + b; e3 = (e3 >= 0.f) ? e3 : kNeg * e3;
    float am = 0.25f * (expf(e0 - m0) / (dn.x + kEps) + expf(e1 - m1) / (dn.y + kEps) +
                        expf(e2 - m2) / (dn.z + kEps) + expf(e3 - m3) / (dn.w + kEps));
    if (dt) ((float*)d_out)[alpha_off + e] = am;
    else    ((__hip_bfloat16*)d_out)[alpha_off + e] = __float2bfloat16(am);
  }
}

extern "C" void kernel_launch(void* const* d_in, const int* in_sizes, int n_in,
                              void* d_out, int out_size, void* d_ws, size_t ws_size,
                              hipStream_t stream) {
  const void* H     = d_in[0];
  const int*  ei    = (const int*)d_in[1];
  const void* sim1  = d_in[2];
  const void* W     = d_in[3];
  const void* a_src = d_in[4];
  const void* a_dst = d_in[5];
  const void* msg_w = d_in[6];
  const int N = in_sizes[0] / 256;
  const int E = in_sizes[2];
  const int NB = (N + 255) / 256;  // scan blocks (<=1024 supported)

  char* base     = (char*)d_ws;
  float* s_src   = (float*)base;  base += (size_t)N * 4 * 4;
  float* s_dst   = (float*)base;  base += (size_t)N * 4 * 4;
  __half* msgb   = (__half*)base; base += (size_t)N * DK * 2;
  __half* Hb     = (__half*)base; base += (size_t)N * 128 * 2;
  float* denom   = (float*)base;  base += (size_t)N * 4 * 4;
  unsigned short* Bhi = (unsigned short*)base; base += 32768 * 2;  // 64 KB
  unsigned short* Blo = (unsigned short*)base; base += 32768 * 2;  // 64 KB
  int* deg       = (int*)base;    base += (size_t)N * 4;   // <- zeroed from here
  unsigned* gmax = (unsigned*)base; base += 4 * 4;
  int* eflag     = (int*)base;    base += 4;
  int* dflag     = (int*)base;    base += 4;               // <- zeroed to here
  int* row_ptr   = (int*)base;    base += (size_t)(N + 2) * 4;  // +1 pad for 8B align
  int* cursor    = (int*)base;    base += (size_t)N * 4;
  int* bsum      = (int*)base;    base += 1024 * 4;
  int2* pack     = (int2*)base;   base += (size_t)E * 8;
  int* src_i     = (int*)base;    base += (size_t)E * 4;
  int* dst_i     = (int*)base;    base += (size_t)E * 4;
  float* af      = (float*)base;  base += 256 * 4;
  float* msgwf   = (float*)base;  base += 1024 * 4;

  hipMemsetAsync(deg, 0, (size_t)(N + 6) * sizeof(int), stream);

  k_detect<<<512, 256, 0, stream>>>(ei, (const unsigned*)H, eflag, dflag, E, 131072);
  k_cvt<<<(E + 255) / 256, 256, 0, stream>>>(ei, eflag, src_i, dst_i, deg, E);
  k_wparams<<<133, 256, 0, stream>>>(W, Bhi, Blo, a_src, a_dst, msg_w, af, msgwf, dflag);
  k_proj<<<(N + 63) / 64, 256, 0, stream>>>(H, Bhi, Blo, dflag, af, msgwf,
                                            s_src, s_dst, msgb, Hb, N);
  k_scan1<<<NB, 256, 0, stream>>>(deg, bsum, N);
  k_scan2<<<1, 1024, 0, stream>>>(bsum, NB);
  k_scan3<<<NB, 256, 0, stream>>>(deg, bsum, row_ptr, cursor, N);
  k_fillog<<<(E + 255) / 256, 256, 0, stream>>>(src_i, dst_i, sim1, dflag, s_src, s_dst,
                                                cursor, pack, gmax, E);
  k_out<<<(int)(((size_t)N * 64 + 255) / 256), 256, 0, stream>>>(
      row_ptr, pack, s_src, s_dst, gmax, (const unsigned*)Hb, dflag, denom, d_out, N);
  k_edge<<<(int)(((long long)E * 16 + 255) / 256), 256, 0, stream>>>(
      src_i, dst_i, sim1, dflag, s_src, s_dst, denom, gmax, (const __half2*)msgb,
      d_out, N, E);
}

// Round 7
// 465.840 us; speedup vs baseline: 2.1344x; 1.0255x over previous
//
#include <hip/hip_runtime.h>
#include <hip/hip_bf16.h>
#include <hip/hip_fp16.h>
#include <float.h>

#define HEADS 4
#define DK 32

static constexpr float kBeta = 1.0f;
static constexpr float kNeg  = 0.2f;
static constexpr float kEps  = 1e-12f;

typedef __bf16 bf16x8 __attribute__((ext_vector_type(8)));
typedef float  f32x4  __attribute__((ext_vector_type(4)));

__device__ __forceinline__ float bf2f(unsigned short v) {
  return __uint_as_float((unsigned)v << 16);
}
// round-to-nearest-even f32 -> bf16 bits
__device__ __forceinline__ unsigned short f2bf(float f) {
  unsigned u = __float_as_uint(f);
  unsigned r = u + 0x7FFFu + ((u >> 16) & 1u);
  return (unsigned short)(r >> 16);
}
// order-preserving float <-> uint key for atomicMax
__device__ __forceinline__ unsigned fkey(float x) {
  unsigned u = __float_as_uint(x);
  return (u & 0x80000000u) ? ~u : (u | 0x80000000u);
}
__device__ __forceinline__ float funkey(unsigned k) {
  unsigned u = (k & 0x80000000u) ? (k & 0x7fffffffu) : ~k;
  return __uint_as_float(u);
}
__device__ __forceinline__ bf16x8 as8(uint4 v) {
  union { uint4 u; bf16x8 b; } x; x.u = v; return x.b;
}

// ---- K0a: fused detect: edge layout (int64 -> odd words 0) + float dtype -----
__global__ __launch_bounds__(256) void k_detect(const int* __restrict__ ei32,
                                                const unsigned* __restrict__ Hw,
                                                int* __restrict__ eflag,
                                                int* __restrict__ dflag,
                                                int E, int nw) {
  int i = blockIdx.x * 256 + threadIdx.x;
  if (i < 4096 && 2 * i + 1 < 2 * E && ei32[2 * i + 1] != 0) atomicOr(eflag, 1);
  if (i < nw && ((Hw[i] >> 7) & 0xFFu) == 0xFFu) atomicOr(dflag, 1);
}

// ---- K0c: normalize edge index into int32 src/dst + degree histogram ---------
__global__ __launch_bounds__(256) void k_cvt(const int* __restrict__ ei32,
                                             const int* __restrict__ eflag,
                                             int* __restrict__ src_i,
                                             int* __restrict__ dst_i,
                                             int* __restrict__ deg, int E) {
  int i = blockIdx.x * 256 + threadIdx.x;
  if (i >= E) return;
  int s, d;
  if (*eflag) { s = ei32[i];     d = ei32[E + i]; }
  else        { s = ei32[2 * i]; d = ei32[2 * E + 2 * i]; }
  src_i[i] = s;
  dst_i[i] = d;
  atomicAdd(deg + d, 1);
}

// ---- K0d: W -> MFMA B-fragment pack (hi/lo bf16 split) + small params --------
__global__ __launch_bounds__(256) void k_wparams(const void* __restrict__ in,
                                                 unsigned short* __restrict__ Bhi,
                                                 unsigned short* __restrict__ Blo,
                                                 const void* __restrict__ a_src,
                                                 const void* __restrict__ a_dst,
                                                 const void* __restrict__ msg_w,
                                                 float* __restrict__ af,
                                                 float* __restrict__ msgwf,
                                                 const int* __restrict__ dflag) {
  const int dt = *dflag;
  if (blockIdx.x < 128) {
    int i = blockIdx.x * 256 + threadIdx.x;  // i = r*256 + c, r: out-col, c: k
    int r = i >> 8, c = i & 255;
    float v = dt ? ((const float*)in)[i] : bf2f(((const unsigned short*)in)[i]);
    unsigned short hb = f2bf(v);
    unsigned short lb = f2bf(v - bf2f(hb));
    int kt = c >> 5, ct = r >> 4;
    int lane = (((c >> 3) & 3) << 4) | (r & 15);
    int idx = ((kt * 8 + ct) * 64 + lane) * 8 + (c & 7);
    Bhi[idx] = hb;
    Blo[idx] = lb;
  } else {
    int i = (blockIdx.x - 128) * 256 + threadIdx.x;  // [0, 1280)
    if (i < 128) {
      af[i] = dt ? ((const float*)a_src)[i] : bf2f(((const unsigned short*)a_src)[i]);
    } else if (i < 256) {
      int j = i - 128;
      af[i] = dt ? ((const float*)a_dst)[j] : bf2f(((const unsigned short*)a_dst)[j]);
    } else if (i < 1280) {
      int j = i - 256;
      msgwf[j] = dt ? ((const float*)msg_w)[j] : bf2f(((const unsigned short*)msg_w)[j]);
    }
  }
}

// ---- K0e: 3-phase device-wide exclusive scan of deg --------------------------
__global__ __launch_bounds__(256) void k_scan1(const int* __restrict__ deg,
                                               int* __restrict__ bsum, int N) {
  const int t = threadIdx.x;
  int i = blockIdx.x * 256 + t;
  int v = (i < N) ? deg[i] : 0;
#pragma unroll
  for (int off = 32; off; off >>= 1) v += __shfl_xor(v, off);
  __shared__ int red[4];
  if ((t & 63) == 0) red[t >> 6] = v;
  __syncthreads();
  if (t == 0) bsum[blockIdx.x] = red[0] + red[1] + red[2] + red[3];
}
__global__ __launch_bounds__(1024) void k_scan2(int* __restrict__ bsum, int nb) {
  __shared__ int part[1024];
  const int t = threadIdx.x;
  part[t] = (t < nb) ? bsum[t] : 0;
  __syncthreads();
  int own = part[t];
  for (int off = 1; off < 1024; off <<= 1) {
    int v = (t >= off) ? part[t - off] : 0;
    __syncthreads();
    part[t] += v;
    __syncthreads();
  }
  if (t < nb) bsum[t] = part[t] - own;  // exclusive block offset
}
__global__ __launch_bounds__(256) void k_scan3(const int* __restrict__ deg,
                                               const int* __restrict__ bsum,
                                               int* __restrict__ row_ptr,
                                               int* __restrict__ cursor, int N) {
  __shared__ int part[256];
  const int t = threadIdx.x;
  int i = blockIdx.x * 256 + t;
  int v = (i < N) ? deg[i] : 0;
  part[t] = v;
  __syncthreads();
  for (int off = 1; off < 256; off <<= 1) {
    int x = (t >= off) ? part[t - off] : 0;
    __syncthreads();
    part[t] += x;
    __syncthreads();
  }
  int excl = part[t] - v + bsum[blockIdx.x];
  if (i < N) {
    row_ptr[i] = excl;
    cursor[i]  = excl;
    if (i == N - 1) row_ptr[N] = excl + v;
  }
}

// ---- K1: H_proj = H @ W.T via MFMA (32KB LDS two-pass) + register epilogue ---
__global__ __launch_bounds__(256) void k_proj(const void* __restrict__ Hraw,
                                              const unsigned short* __restrict__ Bhi,
                                              const unsigned short* __restrict__ Blo,
                                              const int* __restrict__ dflag,
                                              const float* __restrict__ af,
                                              const float* __restrict__ msgwf,
                                              float* __restrict__ s_src,
                                              float* __restrict__ s_dst,
                                              __half* __restrict__ msgb,
                                              __half* __restrict__ Hb, int N) {
  __shared__ uint4 lds4[2048];  // 32KB: A_hi frags (pass1), A_lo frags (pass2)
  float* ldsF = (float*)lds4;   // epilogue reuse: msgw [j*33+d] + hbar per wave
  const int t = threadIdx.x;
  const int nb = blockIdx.x * 64;
  const int dt = *dflag;
  const int l = t & 63;
  const int wv = t >> 6;
  const int wrow = wv * 16;
  const int c16 = l & 15;
  const int g4 = l >> 4;

  f32x4 acc[8];
#pragma unroll
  for (int ct = 0; ct < 8; ++ct) acc[ct] = (f32x4){0.f, 0.f, 0.f, 0.f};
  const uint4* __restrict__ Bh4 = (const uint4*)Bhi;
  const uint4* __restrict__ Bl4 = (const uint4*)Blo;

  // ---- pass 1: stage A_hi (bf16 path: exact A) ----
  if (dt) {
    const float4* __restrict__ H4 = (const float4*)Hraw;
#pragma unroll
    for (int it = 0; it < 8; ++it) {
      int c = it * 256 + t;
      int row = c >> 5, k8 = c & 31;
      int gr = nb + row;
      float4 v0 = make_float4(0.f, 0.f, 0.f, 0.f), v1 = v0;
      if (gr < N) {
        v0 = H4[(size_t)gr * 64 + k8 * 2];
        v1 = H4[(size_t)gr * 64 + k8 * 2 + 1];
      }
      float f[8] = {v0.x, v0.y, v0.z, v0.w, v1.x, v1.y, v1.z, v1.w};
      unsigned hi[8];
#pragma unroll
      for (int j = 0; j < 8; ++j) hi[j] = f2bf(f[j]);
      lds4[(k8 * 64 + row) ^ (k8 & 7)] =
          make_uint4(hi[0] | (hi[1] << 16), hi[2] | (hi[3] << 16),
                     hi[4] | (hi[5] << 16), hi[6] | (hi[7] << 16));
    }
  } else {
    const uint4* __restrict__ H8 = (const uint4*)Hraw;
#pragma unroll
    for (int it = 0; it < 8; ++it) {
      int c = it * 256 + t;
      int row = c >> 5, k8 = c & 31;
      int gr = nb + row;
      uint4 v = make_uint4(0u, 0u, 0u, 0u);
      if (gr < N) v = H8[(size_t)gr * 32 + k8];
      lds4[(k8 * 64 + row) ^ (k8 & 7)] = v;
    }
  }
  __syncthreads();
  // MFMA pass 1: ahi*bhi (+ ahi*blo for fp32)
#pragma unroll 2
  for (int kt = 0; kt < 8; ++kt) {
    int k8 = kt * 4 + g4;
    int slot = (k8 * 64 + wrow + c16) ^ (k8 & 7);
    bf16x8 ah = as8(lds4[slot]);
#pragma unroll
    for (int ct = 0; ct < 8; ++ct) {
      bf16x8 bh = as8(Bh4[(kt * 8 + ct) * 64 + l]);
      acc[ct] = __builtin_amdgcn_mfma_f32_16x16x32_bf16(ah, bh, acc[ct], 0, 0, 0);
    }
    if (dt) {
#pragma unroll
      for (int ct = 0; ct < 8; ++ct) {
        bf16x8 bl = as8(Bl4[(kt * 8 + ct) * 64 + l]);
        acc[ct] = __builtin_amdgcn_mfma_f32_16x16x32_bf16(ah, bl, acc[ct], 0, 0, 0);
      }
    }
  }
  // ---- pass 2 (fp32 only): restage A_lo, alo*bhi ----
  if (dt) {
    __syncthreads();
    const float4* __restrict__ H4 = (const float4*)Hraw;
#pragma unroll
    for (int it = 0; it < 8; ++it) {
      int c = it * 256 + t;
      int row = c >> 5, k8 = c & 31;
      int gr = nb + row;
      float4 v0 = make_float4(0.f, 0.f, 0.f, 0.f), v1 = v0;
      if (gr < N) {
        v0 = H4[(size_t)gr * 64 + k8 * 2];
        v1 = H4[(size_t)gr * 64 + k8 * 2 + 1];
      }
      float f[8] = {v0.x, v0.y, v0.z, v0.w, v1.x, v1.y, v1.z, v1.w};
      unsigned lo[8];
#pragma unroll
      for (int j = 0; j < 8; ++j) lo[j] = f2bf(f[j] - bf2f(f2bf(f[j])));
      lds4[(k8 * 64 + row) ^ (k8 & 7)] =
          make_uint4(lo[0] | (lo[1] << 16), lo[2] | (lo[3] << 16),
                     lo[4] | (lo[5] << 16), lo[6] | (lo[7] << 16));
    }
    __syncthreads();
#pragma unroll 2
    for (int kt = 0; kt < 8; ++kt) {
      int k8 = kt * 4 + g4;
      int slot = (k8 * 64 + wrow + c16) ^ (k8 & 7);
      bf16x8 al = as8(lds4[slot]);
#pragma unroll
      for (int ct = 0; ct < 8; ++ct) {
        bf16x8 bh = as8(Bh4[(kt * 8 + ct) * 64 + l]);
        acc[ct] = __builtin_amdgcn_mfma_f32_16x16x32_bf16(al, bh, acc[ct], 0, 0, 0);
      }
    }
  }
  __syncthreads();  // all staging reads done; reuse LDS for epilogue

  // ---- epilogue (all from registers / small LDS, fully parallel) ----
  // acc layout: lane l: row = nb + wrow + g4*4 + r, col = ct*16 + c16  [m89]
  // stage msg_w padded [j*33+d] (bank-conflict-free broadcast reads)
#pragma unroll
  for (int i = 0; i < 4; ++i) {
    int idx = t * 4 + i;
    ldsF[(idx >> 5) * 33 + (idx & 31)] = msgwf[idx];
  }
  // hbar (mean over heads) into per-wave padded buffer
  float* hbuf = ldsF + 1056 + wv * 528;  // [16 rows][33]
#pragma unroll
  for (int r = 0; r < 4; ++r) {
    float h0 = 0.25f * (acc[0][r] + acc[2][r] + acc[4][r] + acc[6][r]);
    float h1 = 0.25f * (acc[1][r] + acc[3][r] + acc[5][r] + acc[7][r]);
    hbuf[(g4 * 4 + r) * 33 + c16]      = h0;
    hbuf[(g4 * 4 + r) * 33 + 16 + c16] = h1;
  }
  __syncthreads();  // msg_w visible to all

  // s_src/s_dst dots: partials per lane, reduce across 16-lane group
  float afp[8], afq[8];
#pragma unroll
  for (int ct = 0; ct < 8; ++ct) {
    afp[ct] = af[ct * 16 + c16];
    afq[ct] = af[128 + ct * 16 + c16];
  }
  float pv0[4], pv1[4], pv2[4], pv3[4], qv0[4], qv1[4], qv2[4], qv3[4];
#pragma unroll
  for (int r = 0; r < 4; ++r) {
    pv0[r] = acc[0][r] * afp[0] + acc[1][r] * afp[1];
    pv1[r] = acc[2][r] * afp[2] + acc[3][r] * afp[3];
    pv2[r] = acc[4][r] * afp[4] + acc[5][r] * afp[5];
    pv3[r] = acc[6][r] * afp[6] + acc[7][r] * afp[7];
    qv0[r] = acc[0][r] * afq[0] + acc[1][r] * afq[1];
    qv1[r] = acc[2][r] * afq[2] + acc[3][r] * afq[3];
    qv2[r] = acc[4][r] * afq[4] + acc[5][r] * afq[5];
    qv3[r] = acc[6][r] * afq[6] + acc[7][r] * afq[7];
  }
#pragma unroll
  for (int off = 1; off <= 8; off <<= 1) {
#pragma unroll
    for (int r = 0; r < 4; ++r) {
      pv0[r] += __shfl_xor(pv0[r], off);
      pv1[r] += __shfl_xor(pv1[r], off);
      pv2[r] += __shfl_xor(pv2[r], off);
      pv3[r] += __shfl_xor(pv3[r], off);
      qv0[r] += __shfl_xor(qv0[r], off);
      qv1[r] += __shfl_xor(qv1[r], off);
      qv2[r] += __shfl_xor(qv2[r], off);
      qv3[r] += __shfl_xor(qv3[r], off);
    }
  }
#pragma unroll
  for (int r = 0; r < 4; ++r) {
    int n = nb + wrow + g4 * 4 + r;
    if (n < N) {
      if (c16 < 4) {
        float v = (c16 == 0) ? pv0[r] : (c16 == 1) ? pv1[r]
                 : (c16 == 2) ? pv2[r] : pv3[r];
        s_src[(size_t)n * 4 + c16] = v;
      } else if (c16 < 8) {
        int hh = c16 - 4;
        float v = (hh == 0) ? qv0[r] : (hh == 1) ? qv1[r]
                 : (hh == 2) ? qv2[r] : qv3[r];
        s_dst[(size_t)n * 4 + hh] = v;
      }
    }
  }
  // Hb fp16 copy straight from accumulators
#pragma unroll
  for (int ct = 0; ct < 8; ++ct) {
#pragma unroll
    for (int r = 0; r < 4; ++r) {
      int n = nb + wrow + g4 * 4 + r;
      if (n < N) Hb[(size_t)n * 128 + ct * 16 + c16] = __float2half(acc[ct][r]);
    }
  }
  // msgb: lane -> column j, 8 rows; 8 independent FMA streams
  {
    const int j = l & 31;
    const int r0 = (l >> 5) * 8;
    float res[8] = {0.f, 0.f, 0.f, 0.f, 0.f, 0.f, 0.f, 0.f};
#pragma unroll 4
    for (int d = 0; d < 32; ++d) {
      float mw = ldsF[j * 33 + d];
#pragma unroll
      for (int i = 0; i < 8; ++i) res[i] += hbuf[(r0 + i) * 33 + d] * mw;
    }
#pragma unroll
    for (int i = 0; i < 8; ++i) {
      int n = nb + wrow + r0 + i;
      if (n < N) msgb[(size_t)n * 32 + j] = __float2half(res[i]);
    }
  }
}

// ---- K3: CSR fill + (src,sim) pack + per-head global max ---------------------
__global__ __launch_bounds__(256) void k_fillog(const int* __restrict__ src,
                                                const int* __restrict__ dstv,
                                                const void* __restrict__ sim1,
                                                const int* __restrict__ dflag,
                                                const float* __restrict__ s_src,
                                                const float* __restrict__ s_dst,
                                                int* __restrict__ cursor,
                                                int2* __restrict__ pack,
                                                unsigned* __restrict__ gmax, int E) {
  const int e = blockIdx.x * 256 + threadIdx.x;
  float m0 = -FLT_MAX, m1 = -FLT_MAX, m2 = -FLT_MAX, m3 = -FLT_MAX;
  if (e < E) {
    int s = src[e], d = dstv[e];
    float sv = (*dflag) ? ((const float*)sim1)[e] : bf2f(((const unsigned short*)sim1)[e]);
    int pos = atomicAdd(cursor + d, 1);
    pack[pos] = make_int2(s, __float_as_int(sv));
    float4 ss = *(const float4*)(s_src + (size_t)s * 4);
    float4 sd = *(const float4*)(s_dst + (size_t)d * 4);
    float b = kBeta * sv;
    float e0 = ss.x + sd.x + b; e0 = (e0 >= 0.f) ? e0 : kNeg * e0;
    float e1 = ss.y + sd.y + b; e1 = (e1 >= 0.f) ? e1 : kNeg * e1;
    float e2 = ss.z + sd.z + b; e2 = (e2 >= 0.f) ? e2 : kNeg * e2;
    float e3 = ss.w + sd.w + b; e3 = (e3 >= 0.f) ? e3 : kNeg * e3;
    m0 = e0; m1 = e1; m2 = e2; m3 = e3;
  }
#pragma unroll
  for (int off = 32; off; off >>= 1) {
    m0 = fmaxf(m0, __shfl_xor(m0, off));
    m1 = fmaxf(m1, __shfl_xor(m1, off));
    m2 = fmaxf(m2, __shfl_xor(m2, off));
    m3 = fmaxf(m3, __shfl_xor(m3, off));
  }
  __shared__ float red[4][4];
  if ((threadIdx.x & 63) == 0) {
    int w = threadIdx.x >> 6;
    red[w][0] = m0; red[w][1] = m1; red[w][2] = m2; red[w][3] = m3;
  }
  __syncthreads();
  if (threadIdx.x < 4) {
    int h = threadIdx.x;
    float mm = fmaxf(fmaxf(red[0][h], red[1][h]), fmaxf(red[2][h], red[3][h]));
    atomicMax(gmax + h, fkey(mm));
  }
}

// ---- K5: wave-per-node CSR gather: denom + out rows (no alpha scatter) -------
__global__ __launch_bounds__(256) void k_out(const int* __restrict__ row_ptr,
                                             const int2* __restrict__ pack,
                                             const float* __restrict__ s_src,
                                             const float* __restrict__ s_dst,
                                             const unsigned* __restrict__ gmax,
                                             const unsigned* __restrict__ Hb_u,
                                             const int* __restrict__ dflag,
                                             float* __restrict__ denom,
                                             void* __restrict__ d_out, int N) {
  const int n = (int)((blockIdx.x * 256 + threadIdx.x) >> 6);
  const int l = threadIdx.x & 63;
  if (n >= N) return;
  const int beg = row_ptr[n];
  const int deg = row_ptr[n + 1] - beg;
  const int dt = *dflag;
  const float m0 = funkey(gmax[0]), m1 = funkey(gmax[1]);
  const float m2 = funkey(gmax[2]), m3 = funkey(gmax[3]);
  const float4 sd = *(const float4*)(s_dst + (size_t)n * 4);  // wave-uniform
  float accx = 0.f, accy = 0.f;
  float4 dn = make_float4(0.f, 0.f, 0.f, 0.f);
  int s = 0;
  float4 ev = make_float4(0.f, 0.f, 0.f, 0.f);
  const bool small = (deg <= 64);
  if (small) {
    if (l < deg) {
      int2 p = pack[beg + l];
      s = p.x;
      float sv = __int_as_float(p.y);
      float4 ss = *(const float4*)(s_src + (size_t)s * 4);
      float e0 = ss.x + sd.x + sv; e0 = (e0 >= 0.f) ? e0 : kNeg * e0;
      float e1 = ss.y + sd.y + sv; e1 = (e1 >= 0.f) ? e1 : kNeg * e1;
      float e2 = ss.z + sd.z + sv; e2 = (e2 >= 0.f) ? e2 : kNeg * e2;
      float e3 = ss.w + sd.w + sv; e3 = (e3 >= 0.f) ? e3 : kNeg * e3;
      ev = make_float4(expf(e0 - m0), expf(e1 - m1), expf(e2 - m2), expf(e3 - m3));
      dn = ev;
    }
  } else {
    for (int base = 0; base < deg; base += 64) {
      if (base + l < deg) {
        int2 p = pack[beg + base + l];
        float sv = __int_as_float(p.y);
        float4 ss = *(const float4*)(s_src + (size_t)p.x * 4);
        float e0 = ss.x + sd.x + sv; e0 = (e0 >= 0.f) ? e0 : kNeg * e0;
        float e1 = ss.y + sd.y + sv; e1 = (e1 >= 0.f) ? e1 : kNeg * e1;
        float e2 = ss.z + sd.z + sv; e2 = (e2 >= 0.f) ? e2 : kNeg * e2;
        float e3 = ss.w + sd.w + sv; e3 = (e3 >= 0.f) ? e3 : kNeg * e3;
        dn.x += expf(e0 - m0); dn.y += expf(e1 - m1);
        dn.z += expf(e2 - m2); dn.w += expf(e3 - m3);
      }
    }
  }
#pragma unroll
  for (int off = 32; off; off >>= 1) {
    dn.x += __shfl_xor(dn.x, off);
    dn.y += __shfl_xor(dn.y, off);
    dn.z += __shfl_xor(dn.z, off);
    dn.w += __shfl_xor(dn.w, off);
  }
  if (l == 0) *(float4*)(denom + (size_t)n * 4) = make_float4(dn.x, dn.y, dn.z, dn.w);
  const float i0 = 1.f / (dn.x + kEps), i1 = 1.f / (dn.y + kEps);
  const float i2 = 1.f / (dn.z + kEps), i3 = 1.f / (dn.w + kEps);
  const float myinv = (l < 32) ? ((l < 16) ? i0 : i1) : ((l < 48) ? i2 : i3);
  if (small) {
    for (int i = 0; i < deg; ++i) {
      int si = __shfl(s, i);
      float ax = __shfl(ev.x, i), ay = __shfl(ev.y, i);
      float az = __shfl(ev.z, i), aw = __shfl(ev.w, i);
      float aa = ((l < 32) ? ((l < 16) ? ax : ay) : ((l < 48) ? az : aw)) * myinv;
      unsigned u = Hb_u[(size_t)si * 64 + l];
      float2 f = __half22float2(*(const __half2*)&u);
      accx += aa * f.x;
      accy += aa * f.y;
    }
  } else {
    for (int base = 0; base < deg; base += 64) {
      int cnt = min(64, deg - base);
      int s2 = 0;
      float4 e2v = make_float4(0.f, 0.f, 0.f, 0.f);
      if (l < cnt) {
        int2 p = pack[beg + base + l];
        s2 = p.x;
        float sv = __int_as_float(p.y);
        float4 ss = *(const float4*)(s_src + (size_t)s2 * 4);
        float e0 = ss.x + sd.x + sv; e0 = (e0 >= 0.f) ? e0 : kNeg * e0;
        float e1 = ss.y + sd.y + sv; e1 = (e1 >= 0.f) ? e1 : kNeg * e1;
        float e2 = ss.z + sd.z + sv; e2 = (e2 >= 0.f) ? e2 : kNeg * e2;
        float e3 = ss.w + sd.w + sv; e3 = (e3 >= 0.f) ? e3 : kNeg * e3;
        e2v = make_float4(expf(e0 - m0), expf(e1 - m1), expf(e2 - m2), expf(e3 - m3));
      }
      for (int i = 0; i < cnt; ++i) {
        int si = __shfl(s2, i);
        float ax = __shfl(e2v.x, i), ay = __shfl(e2v.y, i);
        float az = __shfl(e2v.z, i), aw = __shfl(e2v.w, i);
        float aa = ((l < 32) ? ((l < 16) ? ax : ay) : ((l < 48) ? az : aw)) * myinv;
        unsigned u = Hb_u[(size_t)si * 64 + l];
        float2 f = __half22float2(*(const __half2*)&u);
        accx += aa * f.x;
        accy += aa * f.y;
      }
    }
  }
  if (dt) {
    *(float2*)&((float*)d_out)[(size_t)n * 128 + 2 * l] = make_float2(accx, accy);
  } else {
    __hip_bfloat162 b = __float22bfloat162_rn(make_float2(accx, accy));
    *(__hip_bfloat162*)((__hip_bfloat16*)d_out + (size_t)n * 128 + 2 * l) = b;
  }
}

// ---- K6: per-edge epilogue: msg gather + alpha (original order, coalesced) ---
__global__ __launch_bounds__(256) void k_edge(const int* __restrict__ src,
                                              const int* __restrict__ dstv,
                                              const void* __restrict__ sim1,
                                              const int* __restrict__ dflag,
                                              const float* __restrict__ s_src,
                                              const float* __restrict__ s_dst,
                                              const float* __restrict__ denom,
                                              const unsigned* __restrict__ gmax,
                                              const __half2* __restrict__ msgb2,
                                              void* __restrict__ d_out,
                                              int N, int E) {
  long long tid = (long long)blockIdx.x * 256 + threadIdx.x;
  if (tid >= (long long)E * 16) return;
  int e = (int)(tid >> 4), jp = (int)(tid & 15);
  const int dt = *dflag;
  int s = src[e];
  __half2 hv = msgb2[(size_t)s * 16 + jp];
  float2 f = __half22float2(hv);
  const size_t alpha_off = (size_t)N * 128;
  const size_t msg_off = alpha_off + (size_t)E;
  if (dt) {
    *(float2*)&((float*)d_out)[msg_off + (size_t)e * 32 + 2 * jp] = f;
  } else {
    __hip_bfloat162 b = __float22bfloat162_rn(f);
    *(__hip_bfloat162*)((__hip_bfloat16*)d_out + msg_off + (size_t)e * 32 + 2 * jp) = b;
  }
  if (jp == 0) {
    int d = dstv[e];
    float sv = dt ? ((const float*)sim1)[e] : bf2f(((const unsigned short*)sim1)[e]);
    float4 ss = *(const float4*)(s_src + (size_t)s * 4);
    float4 sd = *(const float4*)(s_dst + (size_t)d * 4);
    float4 dn = *(const float4*)(denom + (size_t)d * 4);
    float m0 = funkey(gmax[0]), m1 = funkey(gmax[1]);
    float m2 = funkey(gmax[2]), m3 = funkey(gmax[3]);
    float b = kBeta * sv;
    float e0 = ss.x + sd.x + b; e0 = (e0 >= 0.f) ? e0 : kNeg * e0;
    float e1 = ss.y + sd.y + b; e1 = (e1 >= 0.f) ? e1 : kNeg * e1;
    float e2 = ss.z + sd.z + b; e2 = (e2 >= 0.f) ? e2 : kNeg * e2;
    float e3 = ss.w + sd.w + b; e3 = (e3 >= 0.f) ? e3 : kNeg * e3;
    float am = 0.25f * (expf(e0 - m0) / (dn.x + kEps) + expf(e1 - m1) / (dn.y + kEps) +
                        expf(e2 - m2) / (dn.z + kEps) + expf(e3 - m3) / (dn.w + kEps));
    if (dt) ((float*)d_out)[alpha_off + e] = am;
    else    ((__hip_bfloat16*)d_out)[alpha_off + e] = __float2bfloat16(am);
  }
}

extern "C" void kernel_launch(void* const* d_in, const int* in_sizes, int n_in,
                              void* d_out, int out_size, void* d_ws, size_t ws_size,
                              hipStream_t stream) {
  const void* H     = d_in[0];
  const int*  ei    = (const int*)d_in[1];
  const void* sim1  = d_in[2];
  const void* W     = d_in[3];
  const void* a_src = d_in[4];
  const void* a_dst = d_in[5];
  const void* msg_w = d_in[6];
  const int N = in_sizes[0] / 256;
  const int E = in_sizes[2];
  const int NB = (N + 255) / 256;  // scan blocks (<=1024 supported)

  char* base     = (char*)d_ws;
  float* s_src   = (float*)base;  base += (size_t)N * 4 * 4;
  float* s_dst   = (float*)base;  base += (size_t)N * 4 * 4;
  __half* msgb   = (__half*)base; base += (size_t)N * DK * 2;
  __half* Hb     = (__half*)base; base += (size_t)N * 128 * 2;
  float* denom   = (float*)base;  base += (size_t)N * 4 * 4;
  unsigned short* Bhi = (unsigned short*)base; base += 32768 * 2;  // 64 KB
  unsigned short* Blo = (unsigned short*)base; base += 32768 * 2;  // 64 KB
  int* deg       = (int*)base;    base += (size_t)N * 4;   // <- zeroed from here
  unsigned* gmax = (unsigned*)base; base += 4 * 4;
  int* eflag     = (int*)base;    base += 4;
  int* dflag     = (int*)base;    base += 4;               // <- zeroed to here
  int* row_ptr   = (int*)base;    base += (size_t)(N + 2) * 4;  // +1 pad for 8B align
  int* cursor    = (int*)base;    base += (size_t)N * 4;
  int* bsum      = (int*)base;    base += 1024 * 4;
  int2* pack     = (int2*)base;   base += (size_t)E * 8;
  int* src_i     = (int*)base;    base += (size_t)E * 4;
  int* dst_i     = (int*)base;    base += (size_t)E * 4;
  float* af      = (float*)base;  base += 256 * 4;
  float* msgwf   = (float*)base;  base += 1024 * 4;

  hipMemsetAsync(deg, 0, (size_t)(N + 6) * sizeof(int), stream);

  k_detect<<<512, 256, 0, stream>>>(ei, (const unsigned*)H, eflag, dflag, E, 131072);
  k_cvt<<<(E + 255) / 256, 256, 0, stream>>>(ei, eflag, src_i, dst_i, deg, E);
  k_wparams<<<133, 256, 0, stream>>>(W, Bhi, Blo, a_src, a_dst, msg_w, af, msgwf, dflag);
  k_proj<<<(N + 63) / 64, 256, 0, stream>>>(H, Bhi, Blo, dflag, af, msgwf,
                                            s_src, s_dst, msgb, Hb, N);
  k_scan1<<<NB, 256, 0, stream>>>(deg, bsum, N);
  k_scan2<<<1, 1024, 0, stream>>>(bsum, NB);
  k_scan3<<<NB, 256, 0, stream>>>(deg, bsum, row_ptr, cursor, N);
  k_fillog<<<(E + 255) / 256, 256, 0, stream>>>(src_i, dst_i, sim1, dflag, s_src, s_dst,
                                                cursor, pack, gmax, E);
  k_out<<<(int)(((size_t)N * 64 + 255) / 256), 256, 0, stream>>>(
      row_ptr, pack, s_src, s_dst, gmax, (const unsigned*)Hb, dflag, denom, d_out, N);
  k_edge<<<(int)(((long long)E * 16 + 255) / 256), 256, 0, stream>>>(
      src_i, dst_i, sim1, dflag, s_src, s_dst, denom, gmax, (const __half2*)msgb,
      d_out, N, E);
}